// Round 5
// baseline (3263.273 us; speedup 1.0000x reference)
//
#include <hip/hip_runtime.h>
#include <hip/hip_bf16.h>
#include <stdint.h>

#define TK 64
#define FDIM 16384
#define DDIM 2048
#define NCAP 128
#define LCAP 512
#define TCAND 2.0f

typedef __attribute__((ext_vector_type(8))) short bf16x8;
typedef __attribute__((ext_vector_type(4))) float f32x4;

#define GLL(g, p)                                                        \
  __builtin_amdgcn_global_load_lds(                                      \
      (const __attribute__((address_space(1))) uint32_t*)(g),            \
      (__attribute__((address_space(3))) uint32_t*)(p), 16, 0, 0)

__device__ __forceinline__ unsigned short f2bf(float a) {
  union { float f; uint32_t u; } p; p.f = a;
  uint32_t u = p.u;
  return (unsigned short)((u + 0x7FFFu + ((u >> 16) & 1u)) >> 16);
}
__device__ __forceinline__ float bf2f(unsigned short h) {
  union { uint32_t u; float f; } p; p.u = ((uint32_t)h) << 16; return p.f;
}

// ---------------------------------------------------------------------------
__global__ __launch_bounds__(256) void zero_counts(int* __restrict__ c, int n) {
  int i = blockIdx.x * 256 + threadIdx.x;
  if (i < n) c[i] = 0;
}

// ---------------------------------------------------------------------------
// conv_x: f32 [B][D] -> bf16 hi/lo [B][D]
// ---------------------------------------------------------------------------
__global__ __launch_bounds__(256) void conv_x(
    const float* __restrict__ x, unsigned short* __restrict__ xh,
    unsigned short* __restrict__ xl, int n4)
{
  int i = blockIdx.x * 256 + threadIdx.x;
  const int stride = gridDim.x * 256;
  for (; i < n4; i += stride) {
    float4 v = ((const float4*)x)[i];
    ushort4 h, lo;
    h.x = f2bf(v.x); lo.x = f2bf(v.x - bf2f(h.x));
    h.y = f2bf(v.y); lo.y = f2bf(v.y - bf2f(h.y));
    h.z = f2bf(v.z); lo.z = f2bf(v.z - bf2f(h.z));
    h.w = f2bf(v.w); lo.w = f2bf(v.w - bf2f(h.w));
    ((ushort4*)xh)[i] = h;
    ((ushort4*)xl)[i] = lo;
  }
}

// ---------------------------------------------------------------------------
// conv_w: W_enc f32 [D][F] -> transposed bf16 hi/lo [F][D]
// ---------------------------------------------------------------------------
__global__ __launch_bounds__(256) void conv_w(
    const float* __restrict__ W, unsigned short* __restrict__ wh,
    unsigned short* __restrict__ wl)
{
  __shared__ float t[32][33];
  const int f0 = blockIdx.x * 32, d0 = blockIdx.y * 32;
  const int tr = threadIdx.x >> 3;
  const int tc = (threadIdx.x & 7) * 4;
  float4 v = *(const float4*)(W + (size_t)(d0 + tr) * FDIM + f0 + tc);
  t[tr][tc + 0] = v.x; t[tr][tc + 1] = v.y;
  t[tr][tc + 2] = v.z; t[tr][tc + 3] = v.w;
  __syncthreads();
  float a0 = t[tc + 0][tr], a1 = t[tc + 1][tr];
  float a2 = t[tc + 2][tr], a3 = t[tc + 3][tr];
  ushort4 h, lo;
  h.x = f2bf(a0); lo.x = f2bf(a0 - bf2f(h.x));
  h.y = f2bf(a1); lo.y = f2bf(a1 - bf2f(h.y));
  h.z = f2bf(a2); lo.z = f2bf(a2 - bf2f(h.z));
  h.w = f2bf(a3); lo.w = f2bf(a3 - bf2f(h.w));
  *(ushort4*)(wh + (size_t)(f0 + tr) * DDIM + d0 + tc) = h;
  *(ushort4*)(wl + (size_t)(f0 + tr) * DDIM + d0 + tc) = lo;
}

// ---------------------------------------------------------------------------
// conv_wd: W_dec f32 [F][D] -> bf16 same layout
// ---------------------------------------------------------------------------
__global__ __launch_bounds__(256) void conv_wd(
    const float* __restrict__ W, unsigned short* __restrict__ Wb, int n4)
{
  int i = blockIdx.x * 256 + threadIdx.x;
  const int stride = gridDim.x * 256;
  for (; i < n4; i += stride) {
    float4 v = ((const float4*)W)[i];
    ushort4 h;
    h.x = f2bf(v.x); h.y = f2bf(v.y); h.z = f2bf(v.z); h.w = f2bf(v.w);
    ((ushort4*)Wb)[i] = h;
  }
}

// ---------------------------------------------------------------------------
// Kernel 1: encode GEMM via split-bf16 MFMA (3 products; xl*wl dropped).
// Epilogue emits candidates (z > TCAND) directly to per-row global lists —
// no dense z tensor is ever written.
// ---------------------------------------------------------------------------
__global__ __launch_bounds__(256) void enc_gemm_bf16x3(
    const unsigned short* __restrict__ xh,  // [B][DDIM] bf16
    const unsigned short* __restrict__ xl,
    const unsigned short* __restrict__ wh,  // [FDIM][DDIM] bf16 (W^T)
    const unsigned short* __restrict__ wl,
    const float* __restrict__ bias,         // [FDIM]
    int*   __restrict__ rowCnt,             // [B]
    int*   __restrict__ candIdx,            // [B][LCAP]
    float* __restrict__ candVal)            // [B][LCAP]
{
  __shared__ __align__(16) char smem[32768];  // Ah,Al,Bh,Bl tiles 8KB each
  const int tid = threadIdx.x;
  const int l = tid & 63;
  const int w = tid >> 6;
  const int wm = w >> 1, wn = w & 1;

  // XCD-aware bijective swizzle of the linear block id
  const int nbx = gridDim.x;
  const int lin = blockIdx.y * nbx + blockIdx.x;
  const int nwg = nbx * gridDim.y;
  const int cpx = nwg >> 3;                 // nwg % 8 == 0 guaranteed
  const int swz = (lin & 7) * cpx + (lin >> 3);
  const int row0 = (swz / nbx) * 128;
  const int col0 = (swz % nbx) * 128;

  f32x4 acc[4][4] = {};

  const int sr = tid >> 2;
  const int sg = (tid & 3) ^ ((sr >> 1) & 3);
  const char* gxh = (const char*)xh + (size_t)row0 * 4096 + sg * 16;
  const char* gxl = (const char*)xl + (size_t)row0 * 4096 + sg * 16;
  const char* gwh = (const char*)wh + (size_t)col0 * 4096 + sg * 16;
  const char* gwl = (const char*)wl + (size_t)col0 * 4096 + sg * 16;

  const int lb = (l & 15) * 64 + (((l >> 4) ^ ((l >> 1) & 3)) << 4);
  const int aoff = wm * 4096 + lb;
  const int boff = wn * 4096 + lb;

  for (int k0 = 0; k0 < DDIM; k0 += 32) {
    __syncthreads();
    const size_t kb = (size_t)k0 * 2;
#pragma unroll
    for (int i = 0; i < 2; ++i) {
      const size_t ro = (size_t)(i * 64 + sr) * 4096 + kb;
      char* lp = smem + i * 4096 + w * 1024;
      GLL(gxh + ro, lp);
      GLL(gxl + ro, lp + 8192);
      GLL(gwh + ro, lp + 16384);
      GLL(gwl + ro, lp + 24576);
    }
    __syncthreads();

    bf16x8 ah[4], al[4], bh[4], bl[4];
#pragma unroll
    for (int f = 0; f < 4; ++f) {
      ah[f] = *(const bf16x8*)(smem + aoff + f * 1024);
      al[f] = *(const bf16x8*)(smem + 8192 + aoff + f * 1024);
      bh[f] = *(const bf16x8*)(smem + 16384 + boff + f * 1024);
      bl[f] = *(const bf16x8*)(smem + 24576 + boff + f * 1024);
    }
#pragma unroll
    for (int fm = 0; fm < 4; ++fm)
#pragma unroll
      for (int fn = 0; fn < 4; ++fn) {
        acc[fm][fn] = __builtin_amdgcn_mfma_f32_16x16x32_bf16(
            ah[fm], bh[fn], acc[fm][fn], 0, 0, 0);
        acc[fm][fn] = __builtin_amdgcn_mfma_f32_16x16x32_bf16(
            ah[fm], bl[fn], acc[fm][fn], 0, 0, 0);
        acc[fm][fn] = __builtin_amdgcn_mfma_f32_16x16x32_bf16(
            al[fm], bh[fn], acc[fm][fn], 0, 0, 0);
      }
  }

  // epilogue: bias + relu, threshold-emit candidates to per-row lists
#pragma unroll
  for (int fn = 0; fn < 4; ++fn) {
    const int col = col0 + wn * 64 + fn * 16 + (l & 15);
    const float bb = bias[col];
#pragma unroll
    for (int fm = 0; fm < 4; ++fm) {
#pragma unroll
      for (int q = 0; q < 4; ++q) {
        const int rz = row0 + wm * 64 + fm * 16 + (l >> 4) * 4 + q;
        const float zv = fmaxf(acc[fm][fn][q] + bb, 0.f);
        if (zv > TCAND) {
          int p = atomicAdd(&rowCnt[rz], 1);
          if (p < LCAP) {
            candIdx[(size_t)rz * LCAP + p] = col;
            candVal[(size_t)rz * LCAP + p] = zv;
          }
        }
      }
    }
  }
}

// ---------------------------------------------------------------------------
// Kernel 2: per-row exact top-64 from candidate lists. Rank by strict
// (val desc, idx asc) order = jax tie-break; f64 boundary rescue identical
// in semantics to the verified R2-R4 version. Fallback (never taken in
// practice, exactness guard): recompute z row from f32 x*W_enc on the fly.
// ---------------------------------------------------------------------------
__global__ __launch_bounds__(256) void topk_kernel(
    const int*   __restrict__ rowCnt,
    const int*   __restrict__ candIdxG,  // [B][LCAP]
    const float* __restrict__ candValG,
    const float* __restrict__ x,         // [B][DDIM]
    const float* __restrict__ Wenc,      // [DDIM][FDIM]
    const float* __restrict__ benc,      // [FDIM]
    int*   __restrict__ outIdx,          // [B][TK]
    float* __restrict__ outVal)
{
  const int row = blockIdx.x;
  const int tid = threadIdx.x;

  __shared__ int    cIdx[LCAP];
  __shared__ float  cVal[LCAP];
  __shared__ short  sRank[LCAP];
  __shared__ unsigned char selF[LCAP];
  __shared__ int    cnt;
  __shared__ float  sV64;
  __shared__ int    wList[NCAP];
  __shared__ int    nW, winSel;
  __shared__ double dVals[NCAP];
  __shared__ int    keepFlag[NCAP];
  __shared__ double dred[256];

  int nc = rowCnt[row];
  float Tloc = TCAND;
  const bool fb = (nc < TK) || (nc > LCAP);

  if (!fb) {
    for (int c = tid; c < nc; c += 256) {
      cIdx[c] = candIdxG[(size_t)row * LCAP + c];
      cVal[c] = candValG[(size_t)row * LCAP + c];
    }
    if (tid == 0) cnt = nc;
    __syncthreads();
  } else {
    // fallback: adaptive-threshold recompute of the row's z (exact f32)
    for (int attempt = 0; attempt < 12; ++attempt) {
      if (tid == 0) cnt = 0;
      __syncthreads();
      for (int f = tid; f < FDIM; f += 256) {
        float s = 0.f;
        for (int k = 0; k < DDIM; ++k)
          s = fmaf(x[(size_t)row * DDIM + k], Wenc[(size_t)k * FDIM + f], s);
        float zv = fmaxf(s + benc[f], 0.f);
        if (zv > Tloc) {
          int p = atomicAdd(&cnt, 1);
          if (p < LCAP) { cIdx[p] = f; cVal[p] = zv; }
        }
      }
      __syncthreads();
      nc = cnt;
      __syncthreads();
      if (nc >= TK && nc <= LCAP) break;
      Tloc += (nc > LCAP) ? 0.5f : -0.5f;
    }
    if (nc > LCAP) nc = LCAP;
  }

  // ---- exact rank among candidates (strict total order) ----
  for (int c = tid; c < nc; c += 256) {
    const float vi = cVal[c];
    const int   ii = cIdx[c];
    int rk = 0;
    for (int j = 0; j < nc; ++j) {
      const float vj = cVal[j];
      rk += (vj > vi) || (vj == vi && cIdx[j] < ii);
    }
    sRank[c] = (short)rk;
    selF[c] = (rk < TK) ? 1 : 0;
    if (rk == TK - 1) sV64 = vi;
  }
  __syncthreads();
  const float v64 = sV64;
  const float M = 2.5e-3f;

  // ---- window collection ----
  if (tid == 0) { nW = 0; winSel = 0; }
  __syncthreads();
  for (int c = tid; c < nc; c += 256) {
    if (fabsf(cVal[c] - v64) <= M) {
      int p = atomicAdd(&nW, 1);
      if (p < NCAP) wList[p] = c;
      if (sRank[c] < TK) atomicAdd(&winSel, 1);
    }
  }
  __syncthreads();
  // guard: window may extend below the scan threshold -> recompute scan
  if (v64 - M <= Tloc) {
    for (int f = tid; f < FDIM; f += 256) {
      float s = 0.f;
      for (int k = 0; k < DDIM; ++k)
        s = fmaf(x[(size_t)row * DDIM + k], Wenc[(size_t)k * FDIM + f], s);
      float zv = fmaxf(s + benc[f], 0.f);
      if (zv <= Tloc && fabsf(zv - v64) <= M) {
        int p = atomicAdd(&cnt, 1);
        if (p < LCAP) {
          cIdx[p] = f; cVal[p] = zv;
          sRank[p] = (short)LCAP; selF[p] = 0;
          int pw = atomicAdd(&nW, 1);
          if (pw < NCAP) wList[pw] = p;
        }
      }
    }
    __syncthreads();
    nc = (cnt < LCAP) ? cnt : LCAP;
  }
  const int nw = (nW < NCAP) ? nW : NCAP;

  // ---- f64 boundary rescue ----
  if (nw > winSel) {
    for (int c = 0; c < nw; ++c) {
      const int f = cIdx[wList[c]];
      double part = 0.0;
      for (int k = tid; k < DDIM; k += 256)
        part += (double)x[(size_t)row * DDIM + k] *
                (double)Wenc[(size_t)k * FDIM + f];
      dred[tid] = part;
      __syncthreads();
      for (int s = 128; s > 0; s >>= 1) {
        if (tid < s) dred[tid] += dred[tid + s];
        __syncthreads();
      }
      if (tid == 0) dVals[c] = dred[0] + (double)benc[f];
      __syncthreads();
    }
    if (tid == 0) {
      for (int c = 0; c < nw; ++c) keepFlag[c] = 0;
      int take = winSel < nw ? winSel : nw;
      for (int t = 0; t < take; ++t) {
        int best = -1;
        for (int c = 0; c < nw; ++c) {
          if (keepFlag[c]) continue;
          if (best < 0 || dVals[c] > dVals[best] ||
              (dVals[c] == dVals[best] && cIdx[wList[c]] < cIdx[wList[best]]))
            best = c;
        }
        keepFlag[best] = 1;
      }
      for (int c = 0; c < nw; ++c) selF[wList[c]] = (unsigned char)keepFlag[c];
    }
    __syncthreads();
  }

  // ---- emit 64 (idx,val) pairs ordered by feature idx ----
  for (int c = tid; c < nc; c += 256) {
    if (selF[c]) {
      const int myIdx = cIdx[c];
      int pos = 0;
      for (int j = 0; j < nc; ++j)
        pos += (selF[j] && cIdx[j] < myIdx);
      outIdx[(size_t)row * TK + pos] = myIdx;
      outVal[(size_t)row * TK + pos] = cVal[c];
    }
  }
}

// ---------------------------------------------------------------------------
// Kernel 3: decode  recon = sparse_z @ W_dec(bf16) + b_dec.  Block per row.
// ---------------------------------------------------------------------------
__global__ __launch_bounds__(256) void decode_kernel(
    const int*   __restrict__ idxL,
    const float* __restrict__ valL,
    const unsigned short* __restrict__ Wdb,  // [FDIM][DDIM] bf16
    const float* __restrict__ bd,
    float* __restrict__ out)
{
  const int row = blockIdx.x;
  const int tid = threadIdx.x;
  __shared__ int   si[TK];
  __shared__ float sv[TK];
  if (tid < TK) {
    si[tid] = idxL[(size_t)row * TK + tid];
    sv[tid] = valL[(size_t)row * TK + tid];
  }
  __syncthreads();

  float a[8];
  float4 b0 = ((const float4*)bd)[tid * 2];
  float4 b1 = ((const float4*)bd)[tid * 2 + 1];
  a[0] = b0.x; a[1] = b0.y; a[2] = b0.z; a[3] = b0.w;
  a[4] = b1.x; a[5] = b1.y; a[6] = b1.z; a[7] = b1.w;

#pragma unroll 4
  for (int t = 0; t < TK; ++t) {
    const int f = si[t];
    const float v = sv[t];
    bf16x8 wv = *(const bf16x8*)(Wdb + (size_t)f * DDIM + tid * 8);
#pragma unroll
    for (int j = 0; j < 8; ++j) {
      float w = bf2f((unsigned short)wv[j]);
      a[j] = fmaf(v, w, a[j]);
    }
  }
  float4* orow = (float4*)(out + (size_t)row * DDIM + tid * 8);
  orow[0] = make_float4(a[0], a[1], a[2], a[3]);
  orow[1] = make_float4(a[4], a[5], a[6], a[7]);
}

// ---------------------------------------------------------------------------
extern "C" void kernel_launch(void* const* d_in, const int* in_sizes, int n_in,
                              void* d_out, int out_size, void* d_ws, size_t ws_size,
                              hipStream_t stream) {
  const float* x    = (const float*)d_in[0];
  const float* Wenc = (const float*)d_in[1];
  const float* benc = (const float*)d_in[2];
  const float* Wdec = (const float*)d_in[3];
  const float* bdec = (const float*)d_in[4];
  float* out = (float*)d_out;

  const int D = in_sizes[4];          // 2048
  const int B = in_sizes[0] / D;      // 8192

  // ws layout
  char* ws = (char*)d_ws;
  size_t off = 0;
  int*   idxL = (int*)ws;            off += (size_t)B * TK * 4;
  float* valL = (float*)(ws + off);  off += (size_t)B * TK * 4;
  off = (off + 255) & ~(size_t)255;
  unsigned short* wth = (unsigned short*)(ws + off); off += (size_t)FDIM * DDIM * 2;
  unsigned short* wtl = (unsigned short*)(ws + off); off += (size_t)FDIM * DDIM * 2;
  unsigned short* xh  = (unsigned short*)(ws + off); off += (size_t)B * DDIM * 2;
  unsigned short* xl  = (unsigned short*)(ws + off); off += (size_t)B * DDIM * 2;
  unsigned short* wdb = (unsigned short*)(ws + off); off += (size_t)FDIM * DDIM * 2;
  off = (off + 255) & ~(size_t)255;
  int*   rowCnt  = (int*)(ws + off);   off += (size_t)B * 4;
  int*   candIdx = (int*)(ws + off);   off += (size_t)B * LCAP * 4;
  float* candVal = (float*)(ws + off); off += (size_t)B * LCAP * 4;

  zero_counts<<<(B + 255) / 256, 256, 0, stream>>>(rowCnt, B);
  conv_x<<<2048, 256, 0, stream>>>(x, xh, xl, B * D / 4);
  conv_w<<<dim3(FDIM / 32, DDIM / 32), 256, 0, stream>>>(Wenc, wth, wtl);
  conv_wd<<<2048, 256, 0, stream>>>(Wdec, wdb, FDIM * DDIM / 4);

  dim3 g(FDIM / 128, B / 128);
  enc_gemm_bf16x3<<<g, 256, 0, stream>>>(xh, xl, wth, wtl, benc,
                                         rowCnt, candIdx, candVal);
  topk_kernel<<<B, 256, 0, stream>>>(rowCnt, candIdx, candVal, x, Wenc, benc,
                                     idxL, valL);
  decode_kernel<<<B, 256, 0, stream>>>(idxL, valL, wdb, bdec, out);
}

// Round 6
// 2722.170 us; speedup vs baseline: 1.1988x; 1.1988x over previous
//
#include <hip/hip_runtime.h>
#include <hip/hip_bf16.h>
#include <stdint.h>

#define TK 64
#define FDIM 16384
#define DDIM 2048
#define NCAP 128
#define CCAP 320

typedef __attribute__((ext_vector_type(8))) short bf16x8;
typedef __attribute__((ext_vector_type(4))) float f32x4;

#define GLL(g, p)                                                        \
  __builtin_amdgcn_global_load_lds(                                      \
      (const __attribute__((address_space(1))) uint32_t*)(g),            \
      (__attribute__((address_space(3))) uint32_t*)(p), 16, 0, 0)

__device__ __forceinline__ unsigned short f2bf(float a) {
  union { float f; uint32_t u; } p; p.f = a;
  uint32_t u = p.u;
  return (unsigned short)((u + 0x7FFFu + ((u >> 16) & 1u)) >> 16);
}
__device__ __forceinline__ float bf2f(unsigned short h) {
  union { uint32_t u; float f; } p; p.u = ((uint32_t)h) << 16; return p.f;
}

// ---------------------------------------------------------------------------
// conv_x: f32 [B][D] -> bf16 hi/lo [B][D]
// ---------------------------------------------------------------------------
__global__ __launch_bounds__(256) void conv_x(
    const float* __restrict__ x, unsigned short* __restrict__ xh,
    unsigned short* __restrict__ xl, int n4)
{
  int i = blockIdx.x * 256 + threadIdx.x;
  const int stride = gridDim.x * 256;
  for (; i < n4; i += stride) {
    float4 v = ((const float4*)x)[i];
    ushort4 h, lo;
    h.x = f2bf(v.x); lo.x = f2bf(v.x - bf2f(h.x));
    h.y = f2bf(v.y); lo.y = f2bf(v.y - bf2f(h.y));
    h.z = f2bf(v.z); lo.z = f2bf(v.z - bf2f(h.z));
    h.w = f2bf(v.w); lo.w = f2bf(v.w - bf2f(h.w));
    ((ushort4*)xh)[i] = h;
    ((ushort4*)xl)[i] = lo;
  }
}

// ---------------------------------------------------------------------------
// conv_w: W_enc f32 [D][F] -> transposed bf16 hi/lo [F][D]
// ---------------------------------------------------------------------------
__global__ __launch_bounds__(256) void conv_w(
    const float* __restrict__ W, unsigned short* __restrict__ wh,
    unsigned short* __restrict__ wl)
{
  __shared__ float t[32][33];
  const int f0 = blockIdx.x * 32, d0 = blockIdx.y * 32;
  const int tr = threadIdx.x >> 3;
  const int tc = (threadIdx.x & 7) * 4;
  float4 v = *(const float4*)(W + (size_t)(d0 + tr) * FDIM + f0 + tc);
  t[tr][tc + 0] = v.x; t[tr][tc + 1] = v.y;
  t[tr][tc + 2] = v.z; t[tr][tc + 3] = v.w;
  __syncthreads();
  float a0 = t[tc + 0][tr], a1 = t[tc + 1][tr];
  float a2 = t[tc + 2][tr], a3 = t[tc + 3][tr];
  ushort4 h, lo;
  h.x = f2bf(a0); lo.x = f2bf(a0 - bf2f(h.x));
  h.y = f2bf(a1); lo.y = f2bf(a1 - bf2f(h.y));
  h.z = f2bf(a2); lo.z = f2bf(a2 - bf2f(h.z));
  h.w = f2bf(a3); lo.w = f2bf(a3 - bf2f(h.w));
  *(ushort4*)(wh + (size_t)(f0 + tr) * DDIM + d0 + tc) = h;
  *(ushort4*)(wl + (size_t)(f0 + tr) * DDIM + d0 + tc) = lo;
}

// ---------------------------------------------------------------------------
// conv_wd: W_dec f32 [F][D] -> bf16 same layout
// ---------------------------------------------------------------------------
__global__ __launch_bounds__(256) void conv_wd(
    const float* __restrict__ W, unsigned short* __restrict__ Wb, int n4)
{
  int i = blockIdx.x * 256 + threadIdx.x;
  const int stride = gridDim.x * 256;
  for (; i < n4; i += stride) {
    float4 v = ((const float4*)W)[i];
    ushort4 h;
    h.x = f2bf(v.x); h.y = f2bf(v.y); h.z = f2bf(v.z); h.w = f2bf(v.w);
    ((ushort4*)Wb)[i] = h;
  }
}

// ---------------------------------------------------------------------------
// Kernel 1: encode GEMM via split-bf16 MFMA (3 products; xl*wl dropped).
// 128x128 tile, BK=32, 4 waves, global_load_lds + XOR source/read swizzle.
// XCD-aware bijective block swizzle. (Measured-good R4 version, unchanged.)
// ---------------------------------------------------------------------------
__global__ __launch_bounds__(256) void enc_gemm_bf16x3(
    const unsigned short* __restrict__ xh,  // [Rchunk][DDIM] bf16
    const unsigned short* __restrict__ xl,
    const unsigned short* __restrict__ wh,  // [FDIM][DDIM] bf16 (W^T)
    const unsigned short* __restrict__ wl,
    const float* __restrict__ bias,         // [FDIM]
    float* __restrict__ Cz)                 // [Rchunk][FDIM]
{
  __shared__ __align__(16) char smem[32768];  // Ah,Al,Bh,Bl tiles 8KB each
  const int tid = threadIdx.x;
  const int l = tid & 63;
  const int w = tid >> 6;
  const int wm = w >> 1, wn = w & 1;

  const int nbx = gridDim.x;
  const int lin = blockIdx.y * nbx + blockIdx.x;
  const int nwg = nbx * gridDim.y;
  const int cpx = nwg >> 3;                 // nwg % 8 == 0 guaranteed
  const int swz = (lin & 7) * cpx + (lin >> 3);
  const int row0 = (swz / nbx) * 128;
  const int col0 = (swz % nbx) * 128;

  f32x4 acc[4][4] = {};

  const int sr = tid >> 2;
  const int sg = (tid & 3) ^ ((sr >> 1) & 3);
  const char* gxh = (const char*)xh + (size_t)row0 * 4096 + sg * 16;
  const char* gxl = (const char*)xl + (size_t)row0 * 4096 + sg * 16;
  const char* gwh = (const char*)wh + (size_t)col0 * 4096 + sg * 16;
  const char* gwl = (const char*)wl + (size_t)col0 * 4096 + sg * 16;

  const int lb = (l & 15) * 64 + (((l >> 4) ^ ((l >> 1) & 3)) << 4);
  const int aoff = wm * 4096 + lb;
  const int boff = wn * 4096 + lb;

  for (int k0 = 0; k0 < DDIM; k0 += 32) {
    __syncthreads();
    const size_t kb = (size_t)k0 * 2;
#pragma unroll
    for (int i = 0; i < 2; ++i) {
      const size_t ro = (size_t)(i * 64 + sr) * 4096 + kb;
      char* lp = smem + i * 4096 + w * 1024;
      GLL(gxh + ro, lp);
      GLL(gxl + ro, lp + 8192);
      GLL(gwh + ro, lp + 16384);
      GLL(gwl + ro, lp + 24576);
    }
    __syncthreads();

    bf16x8 ah[4], al[4], bh[4], bl[4];
#pragma unroll
    for (int f = 0; f < 4; ++f) {
      ah[f] = *(const bf16x8*)(smem + aoff + f * 1024);
      al[f] = *(const bf16x8*)(smem + 8192 + aoff + f * 1024);
      bh[f] = *(const bf16x8*)(smem + 16384 + boff + f * 1024);
      bl[f] = *(const bf16x8*)(smem + 24576 + boff + f * 1024);
    }
#pragma unroll
    for (int fm = 0; fm < 4; ++fm)
#pragma unroll
      for (int fn = 0; fn < 4; ++fn) {
        acc[fm][fn] = __builtin_amdgcn_mfma_f32_16x16x32_bf16(
            ah[fm], bh[fn], acc[fm][fn], 0, 0, 0);
        acc[fm][fn] = __builtin_amdgcn_mfma_f32_16x16x32_bf16(
            ah[fm], bl[fn], acc[fm][fn], 0, 0, 0);
        acc[fm][fn] = __builtin_amdgcn_mfma_f32_16x16x32_bf16(
            al[fm], bh[fn], acc[fm][fn], 0, 0, 0);
      }
  }

#pragma unroll
  for (int fn = 0; fn < 4; ++fn) {
    const int col = col0 + wn * 64 + fn * 16 + (l & 15);
    const float bb = bias[col];
#pragma unroll
    for (int fm = 0; fm < 4; ++fm) {
#pragma unroll
      for (int q = 0; q < 4; ++q) {
        const int rz = row0 + wm * 64 + fm * 16 + (l >> 4) * 4 + q;
        Cz[(size_t)rz * FDIM + col] = fmaxf(acc[fm][fn][q] + bb, 0.f);
      }
    }
  }
}

// ---------------------------------------------------------------------------
// Kernel 2: per-row exact top-64 via threshold candidate pruning (R4,
// measured ~0.2ms, verified). f64 boundary rescue semantics unchanged.
// ---------------------------------------------------------------------------
__global__ __launch_bounds__(256) void topk_kernel(
    const float* __restrict__ z,     // [Rchunk, FDIM]
    const float* __restrict__ x,     // [Rchunk, DDIM] (chunk-offset)
    const float* __restrict__ Wenc,  // [DDIM, FDIM]
    const float* __restrict__ benc,  // [FDIM]
    int*   __restrict__ outIdx,      // [Rchunk, TK]
    float* __restrict__ outVal)      // [Rchunk, TK]
{
  const int row = blockIdx.x;
  const int tid = threadIdx.x;
  const float* zr = z + (size_t)row * FDIM;

  __shared__ int    cIdx[CCAP];
  __shared__ float  cVal[CCAP];
  __shared__ short  sRank[CCAP];
  __shared__ unsigned char selF[CCAP];
  __shared__ int    cnt;
  __shared__ float  sV64;
  __shared__ int    wList[NCAP];
  __shared__ int    nW, winSel;
  __shared__ double dVals[NCAP];
  __shared__ int    keepFlag[NCAP];
  __shared__ double dred[256];

  // ---- candidate scan with bounded threshold retry ----
  float T = 2.25f;
  int nc = 0;
  for (int attempt = 0; attempt < 16; ++attempt) {
    if (tid == 0) cnt = 0;
    __syncthreads();
    for (int i4 = tid; i4 < FDIM / 4; i4 += 256) {
      float4 v = ((const float4*)zr)[i4];
      const int i0 = i4 * 4;
      if (v.x > T) { int p = atomicAdd(&cnt, 1); if (p < CCAP) { cIdx[p] = i0 + 0; cVal[p] = v.x; } }
      if (v.y > T) { int p = atomicAdd(&cnt, 1); if (p < CCAP) { cIdx[p] = i0 + 1; cVal[p] = v.y; } }
      if (v.z > T) { int p = atomicAdd(&cnt, 1); if (p < CCAP) { cIdx[p] = i0 + 2; cVal[p] = v.z; } }
      if (v.w > T) { int p = atomicAdd(&cnt, 1); if (p < CCAP) { cIdx[p] = i0 + 3; cVal[p] = v.w; } }
    }
    __syncthreads();
    nc = cnt;
    __syncthreads();
    if (nc >= TK && nc <= CCAP) break;
    T += (nc > CCAP) ? 0.25f : -0.5f;
  }
  if (nc > CCAP) nc = CCAP;

  // ---- exact rank among candidates (strict total order) ----
  for (int c = tid; c < nc; c += 256) {
    const float vi = cVal[c];
    const int   ii = cIdx[c];
    int rk = 0;
    for (int j = 0; j < nc; ++j) {
      const float vj = cVal[j];
      rk += (vj > vi) || (vj == vi && cIdx[j] < ii);
    }
    sRank[c] = (short)rk;
    selF[c] = (rk < TK) ? 1 : 0;
    if (rk == TK - 1) sV64 = vi;
  }
  __syncthreads();
  const float v64 = sV64;
  const float M = 2.5e-3f;

  // ---- window collection ----
  if (tid == 0) { nW = 0; winSel = 0; }
  __syncthreads();
  for (int c = tid; c < nc; c += 256) {
    if (fabsf(cVal[c] - v64) <= M) {
      int p = atomicAdd(&nW, 1);
      if (p < NCAP) wList[p] = c;
      if (sRank[c] < TK) atomicAdd(&winSel, 1);
    }
  }
  __syncthreads();
  // guard: if window bottom could fall below scan threshold, rescan row
  if (v64 - M <= T) {
    for (int i4 = tid; i4 < FDIM / 4; i4 += 256) {
      float4 v = ((const float4*)zr)[i4];
      const int i0 = i4 * 4;
      float vv[4] = {v.x, v.y, v.z, v.w};
#pragma unroll
      for (int q = 0; q < 4; ++q) {
        if (vv[q] <= T && fabsf(vv[q] - v64) <= M) {
          int p = atomicAdd(&cnt, 1);
          if (p < CCAP) {
            cIdx[p] = i0 + q; cVal[p] = vv[q];
            sRank[p] = (short)CCAP; selF[p] = 0;
            int pw = atomicAdd(&nW, 1);
            if (pw < NCAP) wList[pw] = p;
          }
        }
      }
    }
    __syncthreads();
    nc = (cnt < CCAP) ? cnt : CCAP;
  }
  const int nw = (nW < NCAP) ? nW : NCAP;

  // ---- f64 boundary rescue ----
  if (nw > winSel) {
    for (int c = 0; c < nw; ++c) {
      const int f = cIdx[wList[c]];
      double part = 0.0;
      for (int k = tid; k < DDIM; k += 256)
        part += (double)x[(size_t)row * DDIM + k] *
                (double)Wenc[(size_t)k * FDIM + f];
      dred[tid] = part;
      __syncthreads();
      for (int s = 128; s > 0; s >>= 1) {
        if (tid < s) dred[tid] += dred[tid + s];
        __syncthreads();
      }
      if (tid == 0) dVals[c] = dred[0] + (double)benc[f];
      __syncthreads();
    }
    if (tid == 0) {
      for (int c = 0; c < nw; ++c) keepFlag[c] = 0;
      int take = winSel < nw ? winSel : nw;
      for (int t = 0; t < take; ++t) {
        int best = -1;
        for (int c = 0; c < nw; ++c) {
          if (keepFlag[c]) continue;
          if (best < 0 || dVals[c] > dVals[best] ||
              (dVals[c] == dVals[best] && cIdx[wList[c]] < cIdx[wList[best]]))
            best = c;
        }
        keepFlag[best] = 1;
      }
      for (int c = 0; c < nw; ++c) selF[wList[c]] = (unsigned char)keepFlag[c];
    }
    __syncthreads();
  }

  // ---- emit 64 (idx,val) pairs ordered by feature idx ----
  for (int c = tid; c < nc; c += 256) {
    if (selF[c]) {
      const int myIdx = cIdx[c];
      int pos = 0;
      for (int j = 0; j < nc; ++j)
        pos += (selF[j] && cIdx[j] < myIdx);
      outIdx[(size_t)row * TK + pos] = myIdx;
      outVal[(size_t)row * TK + pos] = cVal[c];
    }
  }
}

// ---------------------------------------------------------------------------
// Kernel 3: decode  recon = sparse_z @ W_dec(bf16) + b_dec.  Block per row.
// Traffic halved vs f32 gather (4.3 -> 2.15 GB, L3-resident).
// ---------------------------------------------------------------------------
__global__ __launch_bounds__(256) void decode_kernel(
    const int*   __restrict__ idxL,
    const float* __restrict__ valL,
    const unsigned short* __restrict__ Wdb,  // [FDIM][DDIM] bf16
    const float* __restrict__ bd,
    float* __restrict__ out)
{
  const int row = blockIdx.x;
  const int tid = threadIdx.x;
  __shared__ int   si[TK];
  __shared__ float sv[TK];
  if (tid < TK) {
    si[tid] = idxL[(size_t)row * TK + tid];
    sv[tid] = valL[(size_t)row * TK + tid];
  }
  __syncthreads();

  float a[8];
  float4 b0 = ((const float4*)bd)[tid * 2];
  float4 b1 = ((const float4*)bd)[tid * 2 + 1];
  a[0] = b0.x; a[1] = b0.y; a[2] = b0.z; a[3] = b0.w;
  a[4] = b1.x; a[5] = b1.y; a[6] = b1.z; a[7] = b1.w;

#pragma unroll 4
  for (int t = 0; t < TK; ++t) {
    const int f = si[t];
    const float v = sv[t];
    bf16x8 wv = *(const bf16x8*)(Wdb + (size_t)f * DDIM + tid * 8);
#pragma unroll
    for (int j = 0; j < 8; ++j) {
      float w = bf2f((unsigned short)wv[j]);
      a[j] = fmaf(v, w, a[j]);
    }
  }
  float4* orow = (float4*)(out + (size_t)row * DDIM + tid * 8);
  orow[0] = make_float4(a[0], a[1], a[2], a[3]);
  orow[1] = make_float4(a[4], a[5], a[6], a[7]);
}

// ---------------------------------------------------------------------------
extern "C" void kernel_launch(void* const* d_in, const int* in_sizes, int n_in,
                              void* d_out, int out_size, void* d_ws, size_t ws_size,
                              hipStream_t stream) {
  const float* x    = (const float*)d_in[0];
  const float* Wenc = (const float*)d_in[1];
  const float* benc = (const float*)d_in[2];
  const float* Wdec = (const float*)d_in[3];
  const float* bdec = (const float*)d_in[4];
  float* out = (float*)d_out;

  const int D = in_sizes[4];          // 2048
  const int B = in_sizes[0] / D;      // 8192

  // ws layout: idx | val | Wt_h | Wt_l | x_h | x_l | Wd_b | z(chunked)
  char* ws = (char*)d_ws;
  size_t off = 0;
  int*   idxL = (int*)ws;            off += (size_t)B * TK * 4;
  float* valL = (float*)(ws + off);  off += (size_t)B * TK * 4;
  off = (off + 255) & ~(size_t)255;
  unsigned short* wth = (unsigned short*)(ws + off); off += (size_t)FDIM * DDIM * 2;
  unsigned short* wtl = (unsigned short*)(ws + off); off += (size_t)FDIM * DDIM * 2;
  unsigned short* xh  = (unsigned short*)(ws + off); off += (size_t)B * DDIM * 2;
  unsigned short* xl  = (unsigned short*)(ws + off); off += (size_t)B * DDIM * 2;
  unsigned short* wdb = (unsigned short*)(ws + off); off += (size_t)FDIM * DDIM * 2;
  off = (off + 255) & ~(size_t)255;
  float* z = (float*)(ws + off);

  size_t zBytes = (ws_size > off) ? (ws_size - off) : 0;
  long   zRows  = (long)(zBytes / ((size_t)FDIM * 4));
  int R = (int)((zRows / 128) * 128);
  if (R > B) R = B;
  if (R < 128) R = 128;

  conv_x<<<2048, 256, 0, stream>>>(x, xh, xl, B * D / 4);
  conv_w<<<dim3(FDIM / 32, DDIM / 32), 256, 0, stream>>>(Wenc, wth, wtl);
  conv_wd<<<2048, 256, 0, stream>>>(Wdec, wdb, FDIM * DDIM / 4);

  for (int r0 = 0; r0 < B; r0 += R) {
    int rows = (B - r0 < R) ? (B - r0) : R;
    dim3 g(FDIM / 128, rows / 128);
    enc_gemm_bf16x3<<<g, 256, 0, stream>>>(xh + (size_t)r0 * D,
                                           xl + (size_t)r0 * D,
                                           wth, wtl, benc, z);
    topk_kernel<<<rows, 256, 0, stream>>>(z, x + (size_t)r0 * D, Wenc, benc,
                                          idxL + (size_t)r0 * TK,
                                          valL + (size_t)r0 * TK);
    decode_kernel<<<rows, 256, 0, stream>>>(idxL + (size_t)r0 * TK,
                                            valL + (size_t)r0 * TK,
                                            wdb, bdec, out + (size_t)r0 * D);
  }
}

// Round 7
// 1797.010 us; speedup vs baseline: 1.8159x; 1.5148x over previous
//
#include <hip/hip_runtime.h>
#include <hip/hip_bf16.h>
#include <stdint.h>

#define TK 64
#define FDIM 16384
#define DDIM 2048
#define NCAP 128
#define CCAP 320

typedef __attribute__((ext_vector_type(8))) short bf16x8;
typedef __attribute__((ext_vector_type(4))) float f32x4;

#define GLL(g, p)                                                        \
  __builtin_amdgcn_global_load_lds(                                      \
      (const __attribute__((address_space(1))) uint32_t*)(g),            \
      (__attribute__((address_space(3))) uint32_t*)(p), 16, 0, 0)

__device__ __forceinline__ unsigned short f2bf(float a) {
  union { float f; uint32_t u; } p; p.f = a;
  uint32_t u = p.u;
  return (unsigned short)((u + 0x7FFFu + ((u >> 16) & 1u)) >> 16);
}
__device__ __forceinline__ float bf2f(unsigned short h) {
  union { uint32_t u; float f; } p; p.u = ((uint32_t)h) << 16; return p.f;
}

// ---------------------------------------------------------------------------
// conv_x: f32 [B][D] -> bf16 [B][D]  (hi only — rescue handles the noise)
// ---------------------------------------------------------------------------
__global__ __launch_bounds__(256) void conv_x(
    const float* __restrict__ x, unsigned short* __restrict__ xh, int n4)
{
  int i = blockIdx.x * 256 + threadIdx.x;
  const int stride = gridDim.x * 256;
  for (; i < n4; i += stride) {
    float4 v = ((const float4*)x)[i];
    ushort4 h;
    h.x = f2bf(v.x); h.y = f2bf(v.y); h.z = f2bf(v.z); h.w = f2bf(v.w);
    ((ushort4*)xh)[i] = h;
  }
}

// ---------------------------------------------------------------------------
// conv_w: W_enc f32 [D][F] -> transposed f32 [F][D] AND bf16 [F][D]
// ---------------------------------------------------------------------------
__global__ __launch_bounds__(256) void conv_w(
    const float* __restrict__ W, float* __restrict__ wtf,
    unsigned short* __restrict__ wh)
{
  __shared__ float t[32][33];
  const int f0 = blockIdx.x * 32, d0 = blockIdx.y * 32;
  const int tr = threadIdx.x >> 3;
  const int tc = (threadIdx.x & 7) * 4;
  float4 v = *(const float4*)(W + (size_t)(d0 + tr) * FDIM + f0 + tc);
  t[tr][tc + 0] = v.x; t[tr][tc + 1] = v.y;
  t[tr][tc + 2] = v.z; t[tr][tc + 3] = v.w;
  __syncthreads();
  float a0 = t[tc + 0][tr], a1 = t[tc + 1][tr];
  float a2 = t[tc + 2][tr], a3 = t[tc + 3][tr];
  *(float4*)(wtf + (size_t)(f0 + tr) * DDIM + d0 + tc) =
      make_float4(a0, a1, a2, a3);
  ushort4 h;
  h.x = f2bf(a0); h.y = f2bf(a1); h.z = f2bf(a2); h.w = f2bf(a3);
  *(ushort4*)(wh + (size_t)(f0 + tr) * DDIM + d0 + tc) = h;
}

// ---------------------------------------------------------------------------
// conv_wd: W_dec f32 [F][D] -> bf16 same layout
// ---------------------------------------------------------------------------
__global__ __launch_bounds__(256) void conv_wd(
    const float* __restrict__ W, unsigned short* __restrict__ Wb, int n4)
{
  int i = blockIdx.x * 256 + threadIdx.x;
  const int stride = gridDim.x * 256;
  for (; i < n4; i += stride) {
    float4 v = ((const float4*)W)[i];
    ushort4 h;
    h.x = f2bf(v.x); h.y = f2bf(v.y); h.z = f2bf(v.z); h.w = f2bf(v.w);
    ((ushort4*)Wb)[i] = h;
  }
}

// ---------------------------------------------------------------------------
// Kernel 1: encode GEMM, single-product bf16 MFMA (m97 structure).
// 128x128 tile, BK=32, 4 waves, global_load_lds + XOR source/read swizzle,
// XCD-aware bijective block swizzle. z error ~2.3e-3 — covered by rescue.
// ---------------------------------------------------------------------------
__global__ __launch_bounds__(256) void enc_gemm_bf16(
    const unsigned short* __restrict__ xh,  // [Rchunk][DDIM] bf16
    const unsigned short* __restrict__ wh,  // [FDIM][DDIM] bf16 (W^T)
    const float* __restrict__ bias,         // [FDIM]
    float* __restrict__ Cz)                 // [Rchunk][FDIM]
{
  __shared__ __align__(16) char smem[16384];  // Ah, Bh tiles 8KB each
  const int tid = threadIdx.x;
  const int l = tid & 63;
  const int w = tid >> 6;
  const int wm = w >> 1, wn = w & 1;

  const int nbx = gridDim.x;
  const int lin = blockIdx.y * nbx + blockIdx.x;
  const int nwg = nbx * gridDim.y;
  const int cpx = nwg >> 3;                 // nwg % 8 == 0 guaranteed
  const int swz = (lin & 7) * cpx + (lin >> 3);
  const int row0 = (swz / nbx) * 128;
  const int col0 = (swz % nbx) * 128;

  f32x4 acc[4][4] = {};

  // staging: thread covers LDS 16B slot (r=i*64+(tid>>2), c=tid&3);
  // that slot holds global chunk g = c ^ ((r>>1)&3)
  const int sr = tid >> 2;
  const int sg = (tid & 3) ^ ((sr >> 1) & 3);
  const char* gxh = (const char*)xh + (size_t)row0 * 4096 + sg * 16;
  const char* gwh = (const char*)wh + (size_t)col0 * 4096 + sg * 16;

  // read-side lane base: row (l&15), chunk c = (l>>4) ^ ((l>>1)&3)
  const int lb = (l & 15) * 64 + (((l >> 4) ^ ((l >> 1) & 3)) << 4);
  const int aoff = wm * 4096 + lb;
  const int boff = 8192 + wn * 4096 + lb;

  for (int k0 = 0; k0 < DDIM; k0 += 32) {
    __syncthreads();
    const size_t kb = (size_t)k0 * 2;
#pragma unroll
    for (int i = 0; i < 2; ++i) {
      const size_t ro = (size_t)(i * 64 + sr) * 4096 + kb;
      char* lp = smem + i * 4096 + w * 1024;
      GLL(gxh + ro, lp);
      GLL(gwh + ro, lp + 8192);
    }
    __syncthreads();

    bf16x8 ah[4], bh[4];
#pragma unroll
    for (int f = 0; f < 4; ++f) {
      ah[f] = *(const bf16x8*)(smem + aoff + f * 1024);
      bh[f] = *(const bf16x8*)(smem + boff + f * 1024);
    }
#pragma unroll
    for (int fm = 0; fm < 4; ++fm)
#pragma unroll
      for (int fn = 0; fn < 4; ++fn)
        acc[fm][fn] = __builtin_amdgcn_mfma_f32_16x16x32_bf16(
            ah[fm], bh[fn], acc[fm][fn], 0, 0, 0);
  }

#pragma unroll
  for (int fn = 0; fn < 4; ++fn) {
    const int col = col0 + wn * 64 + fn * 16 + (l & 15);
    const float bb = bias[col];
#pragma unroll
    for (int fm = 0; fm < 4; ++fm) {
#pragma unroll
      for (int q = 0; q < 4; ++q) {
        const int rz = row0 + wm * 64 + fm * 16 + (l >> 4) * 4 + q;
        Cz[(size_t)rz * FDIM + col] = fmaxf(acc[fm][fn][q] + bb, 0.f);
      }
    }
  }
}

// ---------------------------------------------------------------------------
// Kernel 2: per-row exact top-64 via threshold candidate pruning.
// Window M=0.02 covers bf16-GEMM noise (8.7 sigma); f64 boundary rescue
// (now reading coalesced f32 W^T rows) decides exactly at the boundary.
// ---------------------------------------------------------------------------
__global__ __launch_bounds__(256) void topk_kernel(
    const float* __restrict__ z,     // [Rchunk, FDIM]
    const float* __restrict__ x,     // [Rchunk, DDIM] (chunk-offset)
    const float* __restrict__ wtf,   // [FDIM, DDIM] f32 (W^T)
    const float* __restrict__ benc,  // [FDIM]
    int*   __restrict__ outIdx,      // [Rchunk, TK]
    float* __restrict__ outVal)
{
  const int row = blockIdx.x;
  const int tid = threadIdx.x;
  const float* zr = z + (size_t)row * FDIM;

  __shared__ int    cIdx[CCAP];
  __shared__ float  cVal[CCAP];
  __shared__ short  sRank[CCAP];
  __shared__ unsigned char selF[CCAP];
  __shared__ int    cnt;
  __shared__ float  sV64;
  __shared__ int    wList[NCAP];
  __shared__ int    nW, winSel;
  __shared__ double dVals[NCAP];
  __shared__ int    keepFlag[NCAP];
  __shared__ double dred[256];

  // ---- candidate scan with bounded threshold retry ----
  float T = 2.25f;
  int nc = 0;
  for (int attempt = 0; attempt < 16; ++attempt) {
    if (tid == 0) cnt = 0;
    __syncthreads();
    for (int i4 = tid; i4 < FDIM / 4; i4 += 256) {
      float4 v = ((const float4*)zr)[i4];
      const int i0 = i4 * 4;
      if (v.x > T) { int p = atomicAdd(&cnt, 1); if (p < CCAP) { cIdx[p] = i0 + 0; cVal[p] = v.x; } }
      if (v.y > T) { int p = atomicAdd(&cnt, 1); if (p < CCAP) { cIdx[p] = i0 + 1; cVal[p] = v.y; } }
      if (v.z > T) { int p = atomicAdd(&cnt, 1); if (p < CCAP) { cIdx[p] = i0 + 2; cVal[p] = v.z; } }
      if (v.w > T) { int p = atomicAdd(&cnt, 1); if (p < CCAP) { cIdx[p] = i0 + 3; cVal[p] = v.w; } }
    }
    __syncthreads();
    nc = cnt;
    __syncthreads();
    if (nc >= TK && nc <= CCAP) break;
    T += (nc > CCAP) ? 0.25f : -0.5f;
  }
  if (nc > CCAP) nc = CCAP;

  // ---- exact rank among candidates (strict total order) ----
  for (int c = tid; c < nc; c += 256) {
    const float vi = cVal[c];
    const int   ii = cIdx[c];
    int rk = 0;
    for (int j = 0; j < nc; ++j) {
      const float vj = cVal[j];
      rk += (vj > vi) || (vj == vi && cIdx[j] < ii);
    }
    sRank[c] = (short)rk;
    selF[c] = (rk < TK) ? 1 : 0;
    if (rk == TK - 1) sV64 = vi;
  }
  __syncthreads();
  const float v64 = sV64;
  const float M = 0.02f;   // 8.7 sigma of single-product bf16 z noise

  // ---- window collection ----
  if (tid == 0) { nW = 0; winSel = 0; }
  __syncthreads();
  for (int c = tid; c < nc; c += 256) {
    if (fabsf(cVal[c] - v64) <= M) {
      int p = atomicAdd(&nW, 1);
      if (p < NCAP) wList[p] = c;
      if (sRank[c] < TK) atomicAdd(&winSel, 1);
    }
  }
  __syncthreads();
  // guard: if window bottom could fall below scan threshold, rescan row
  if (v64 - M <= T) {
    for (int i4 = tid; i4 < FDIM / 4; i4 += 256) {
      float4 v = ((const float4*)zr)[i4];
      const int i0 = i4 * 4;
      float vv[4] = {v.x, v.y, v.z, v.w};
#pragma unroll
      for (int q = 0; q < 4; ++q) {
        if (vv[q] <= T && fabsf(vv[q] - v64) <= M) {
          int p = atomicAdd(&cnt, 1);
          if (p < CCAP) {
            cIdx[p] = i0 + q; cVal[p] = vv[q];
            sRank[p] = (short)CCAP; selF[p] = 0;
            int pw = atomicAdd(&nW, 1);
            if (pw < NCAP) wList[pw] = p;
          }
        }
      }
    }
    __syncthreads();
    nc = (cnt < CCAP) ? cnt : CCAP;
  }
  const int nw = (nW < NCAP) ? nW : NCAP;

  // ---- f64 boundary rescue (coalesced f32 W^T rows) ----
  if (nw > winSel) {
    for (int c = 0; c < nw; ++c) {
      const int f = cIdx[wList[c]];
      const float* wr = wtf + (size_t)f * DDIM;
      double part = 0.0;
      for (int k = tid; k < DDIM; k += 256)
        part += (double)x[(size_t)row * DDIM + k] * (double)wr[k];
      dred[tid] = part;
      __syncthreads();
      for (int s = 128; s > 0; s >>= 1) {
        if (tid < s) dred[tid] += dred[tid + s];
        __syncthreads();
      }
      if (tid == 0) dVals[c] = dred[0] + (double)benc[f];
      __syncthreads();
    }
    if (tid == 0) {
      for (int c = 0; c < nw; ++c) keepFlag[c] = 0;
      int take = winSel < nw ? winSel : nw;
      for (int t = 0; t < take; ++t) {
        int best = -1;
        for (int c = 0; c < nw; ++c) {
          if (keepFlag[c]) continue;
          if (best < 0 || dVals[c] > dVals[best] ||
              (dVals[c] == dVals[best] && cIdx[wList[c]] < cIdx[wList[best]]))
            best = c;
        }
        keepFlag[best] = 1;
      }
      for (int c = 0; c < nw; ++c) selF[wList[c]] = (unsigned char)keepFlag[c];
    }
    __syncthreads();
  }

  // ---- emit 64 (idx,val) pairs ordered by feature idx ----
  for (int c = tid; c < nc; c += 256) {
    if (selF[c]) {
      const int myIdx = cIdx[c];
      int pos = 0;
      for (int j = 0; j < nc; ++j)
        pos += (selF[j] && cIdx[j] < myIdx);
      outIdx[(size_t)row * TK + pos] = myIdx;
      outVal[(size_t)row * TK + pos] = cVal[c];
    }
  }
}

// ---------------------------------------------------------------------------
// Kernel 3: decode  recon = sparse_z @ W_dec(bf16) + b_dec.  Block per row.
// ---------------------------------------------------------------------------
__global__ __launch_bounds__(256) void decode_kernel(
    const int*   __restrict__ idxL,
    const float* __restrict__ valL,
    const unsigned short* __restrict__ Wdb,  // [FDIM][DDIM] bf16
    const float* __restrict__ bd,
    float* __restrict__ out)
{
  const int row = blockIdx.x;
  const int tid = threadIdx.x;
  __shared__ int   si[TK];
  __shared__ float sv[TK];
  if (tid < TK) {
    si[tid] = idxL[(size_t)row * TK + tid];
    sv[tid] = valL[(size_t)row * TK + tid];
  }
  __syncthreads();

  float a[8];
  float4 b0 = ((const float4*)bd)[tid * 2];
  float4 b1 = ((const float4*)bd)[tid * 2 + 1];
  a[0] = b0.x; a[1] = b0.y; a[2] = b0.z; a[3] = b0.w;
  a[4] = b1.x; a[5] = b1.y; a[6] = b1.z; a[7] = b1.w;

#pragma unroll 4
  for (int t = 0; t < TK; ++t) {
    const int f = si[t];
    const float v = sv[t];
    bf16x8 wv = *(const bf16x8*)(Wdb + (size_t)f * DDIM + tid * 8);
#pragma unroll
    for (int j = 0; j < 8; ++j) {
      float w = bf2f((unsigned short)wv[j]);
      a[j] = fmaf(v, w, a[j]);
    }
  }
  float4* orow = (float4*)(out + (size_t)row * DDIM + tid * 8);
  orow[0] = make_float4(a[0], a[1], a[2], a[3]);
  orow[1] = make_float4(a[4], a[5], a[6], a[7]);
}

// ---------------------------------------------------------------------------
extern "C" void kernel_launch(void* const* d_in, const int* in_sizes, int n_in,
                              void* d_out, int out_size, void* d_ws, size_t ws_size,
                              hipStream_t stream) {
  const float* x    = (const float*)d_in[0];
  const float* Wenc = (const float*)d_in[1];
  const float* benc = (const float*)d_in[2];
  const float* Wdec = (const float*)d_in[3];
  const float* bdec = (const float*)d_in[4];
  float* out = (float*)d_out;

  const int D = in_sizes[4];          // 2048
  const int B = in_sizes[0] / D;      // 8192

  // ws layout: idx | val | Wt_f32 | Wt_bf16 | x_h | Wd_b | z(chunked)
  char* ws = (char*)d_ws;
  size_t off = 0;
  int*   idxL = (int*)ws;            off += (size_t)B * TK * 4;
  float* valL = (float*)(ws + off);  off += (size_t)B * TK * 4;
  off = (off + 255) & ~(size_t)255;
  float*          wtf = (float*)(ws + off);          off += (size_t)FDIM * DDIM * 4;
  unsigned short* wth = (unsigned short*)(ws + off); off += (size_t)FDIM * DDIM * 2;
  unsigned short* xh  = (unsigned short*)(ws + off); off += (size_t)B * DDIM * 2;
  unsigned short* wdb = (unsigned short*)(ws + off); off += (size_t)FDIM * DDIM * 2;
  off = (off + 255) & ~(size_t)255;
  float* z = (float*)(ws + off);

  size_t zBytes = (ws_size > off) ? (ws_size - off) : 0;
  long   zRows  = (long)(zBytes / ((size_t)FDIM * 4));
  int R = (int)((zRows / 128) * 128);
  if (R > B) R = B;
  if (R < 128) R = 128;

  conv_x<<<1024, 256, 0, stream>>>(x, xh, B * D / 4);
  conv_w<<<dim3(FDIM / 32, DDIM / 32), 256, 0, stream>>>(Wenc, wtf, wth);
  conv_wd<<<2048, 256, 0, stream>>>(Wdec, wdb, FDIM * DDIM / 4);

  for (int r0 = 0; r0 < B; r0 += R) {
    int rows = (B - r0 < R) ? (B - r0) : R;
    dim3 g(FDIM / 128, rows / 128);
    enc_gemm_bf16<<<g, 256, 0, stream>>>(xh + (size_t)r0 * D, wth, benc, z);
    topk_kernel<<<rows, 256, 0, stream>>>(z, x + (size_t)r0 * D, wtf, benc,
                                          idxL + (size_t)r0 * TK,
                                          valL + (size_t)r0 * TK);
    decode_kernel<<<rows, 256, 0, stream>>>(idxL + (size_t)r0 * TK,
                                            valL + (size_t)r0 * TK,
                                            wdb, bdec, out + (size_t)r0 * D);
  }
}

// Round 8
// 1599.673 us; speedup vs baseline: 2.0400x; 1.1234x over previous
//
#include <hip/hip_runtime.h>
#include <hip/hip_bf16.h>
#include <stdint.h>

#define TK 64
#define FDIM 16384
#define DDIM 2048
#define NCAP 128
#define CCAP 320

typedef __attribute__((ext_vector_type(8))) short bf16x8;
typedef __attribute__((ext_vector_type(8))) unsigned short u16x8;
typedef __attribute__((ext_vector_type(4))) float f32x4;

#define GLL(g, p)                                                        \
  __builtin_amdgcn_global_load_lds(                                      \
      (const __attribute__((address_space(1))) uint32_t*)(g),            \
      (__attribute__((address_space(3))) uint32_t*)(p), 16, 0, 0)

__device__ __forceinline__ unsigned short f2bf(float a) {
  union { float f; uint32_t u; } p; p.f = a;
  uint32_t u = p.u;
  return (unsigned short)((u + 0x7FFFu + ((u >> 16) & 1u)) >> 16);
}
__device__ __forceinline__ float bf2f(unsigned short h) {
  union { uint32_t u; float f; } p; p.u = ((uint32_t)h) << 16; return p.f;
}

// ---------------------------------------------------------------------------
// conv_x: f32 [B][D] -> bf16 [B][D]
// ---------------------------------------------------------------------------
__global__ __launch_bounds__(256) void conv_x(
    const float* __restrict__ x, unsigned short* __restrict__ xh, int n4)
{
  int i = blockIdx.x * 256 + threadIdx.x;
  const int stride = gridDim.x * 256;
  for (; i < n4; i += stride) {
    float4 v = ((const float4*)x)[i];
    ushort4 h;
    h.x = f2bf(v.x); h.y = f2bf(v.y); h.z = f2bf(v.z); h.w = f2bf(v.w);
    ((ushort4*)xh)[i] = h;
  }
}

// ---------------------------------------------------------------------------
// conv_w: W_enc f32 [D][F] -> transposed f32 [F][D] AND bf16 [F][D]
// ---------------------------------------------------------------------------
__global__ __launch_bounds__(256) void conv_w(
    const float* __restrict__ W, float* __restrict__ wtf,
    unsigned short* __restrict__ wh)
{
  __shared__ float t[32][33];
  const int f0 = blockIdx.x * 32, d0 = blockIdx.y * 32;
  const int tr = threadIdx.x >> 3;
  const int tc = (threadIdx.x & 7) * 4;
  float4 v = *(const float4*)(W + (size_t)(d0 + tr) * FDIM + f0 + tc);
  t[tr][tc + 0] = v.x; t[tr][tc + 1] = v.y;
  t[tr][tc + 2] = v.z; t[tr][tc + 3] = v.w;
  __syncthreads();
  float a0 = t[tc + 0][tr], a1 = t[tc + 1][tr];
  float a2 = t[tc + 2][tr], a3 = t[tc + 3][tr];
  *(float4*)(wtf + (size_t)(f0 + tr) * DDIM + d0 + tc) =
      make_float4(a0, a1, a2, a3);
  ushort4 h;
  h.x = f2bf(a0); h.y = f2bf(a1); h.z = f2bf(a2); h.w = f2bf(a3);
  *(ushort4*)(wh + (size_t)(f0 + tr) * DDIM + d0 + tc) = h;
}

// ---------------------------------------------------------------------------
// conv_wd: W_dec f32 [F][D] -> bf16 same layout
// ---------------------------------------------------------------------------
__global__ __launch_bounds__(256) void conv_wd(
    const float* __restrict__ W, unsigned short* __restrict__ Wb, int n4)
{
  int i = blockIdx.x * 256 + threadIdx.x;
  const int stride = gridDim.x * 256;
  for (; i < n4; i += stride) {
    float4 v = ((const float4*)W)[i];
    ushort4 h;
    h.x = f2bf(v.x); h.y = f2bf(v.y); h.z = f2bf(v.z); h.w = f2bf(v.w);
    ((ushort4*)Wb)[i] = h;
  }
}

// ---------------------------------------------------------------------------
// Kernel 1: encode GEMM, single-product bf16 MFMA (m97 structure),
// z stored as bf16. Block mapping unchanged from measured-good R7.
// ---------------------------------------------------------------------------
__global__ __launch_bounds__(256) void enc_gemm_bf16(
    const unsigned short* __restrict__ xh,  // [Rchunk][DDIM] bf16
    const unsigned short* __restrict__ wh,  // [FDIM][DDIM] bf16 (W^T)
    const float* __restrict__ bias,         // [FDIM]
    unsigned short* __restrict__ Cz)        // [Rchunk][FDIM] bf16
{
  __shared__ __align__(16) char smem[16384];
  const int tid = threadIdx.x;
  const int l = tid & 63;
  const int w = tid >> 6;
  const int wm = w >> 1, wn = w & 1;

  const int nbx = gridDim.x;
  const int lin = blockIdx.y * nbx + blockIdx.x;
  const int nwg = nbx * gridDim.y;
  const int cpx = nwg >> 3;                 // nbx=128 => nwg % 8 == 0
  const int swz = (lin & 7) * cpx + (lin >> 3);
  const int row0 = (swz / nbx) * 128;
  const int col0 = (swz % nbx) * 128;

  f32x4 acc[4][4] = {};

  const int sr = tid >> 2;
  const int sg = (tid & 3) ^ ((sr >> 1) & 3);
  const char* gxh = (const char*)xh + (size_t)row0 * 4096 + sg * 16;
  const char* gwh = (const char*)wh + (size_t)col0 * 4096 + sg * 16;

  const int lb = (l & 15) * 64 + (((l >> 4) ^ ((l >> 1) & 3)) << 4);
  const int aoff = wm * 4096 + lb;
  const int boff = 8192 + wn * 4096 + lb;

  for (int k0 = 0; k0 < DDIM; k0 += 32) {
    __syncthreads();
    const size_t kb = (size_t)k0 * 2;
#pragma unroll
    for (int i = 0; i < 2; ++i) {
      const size_t ro = (size_t)(i * 64 + sr) * 4096 + kb;
      char* lp = smem + i * 4096 + w * 1024;
      GLL(gxh + ro, lp);
      GLL(gwh + ro, lp + 8192);
    }
    __syncthreads();

    bf16x8 ah[4], bh[4];
#pragma unroll
    for (int f = 0; f < 4; ++f) {
      ah[f] = *(const bf16x8*)(smem + aoff + f * 1024);
      bh[f] = *(const bf16x8*)(smem + boff + f * 1024);
    }
#pragma unroll
    for (int fm = 0; fm < 4; ++fm)
#pragma unroll
      for (int fn = 0; fn < 4; ++fn)
        acc[fm][fn] = __builtin_amdgcn_mfma_f32_16x16x32_bf16(
            ah[fm], bh[fn], acc[fm][fn], 0, 0, 0);
  }

#pragma unroll
  for (int fn = 0; fn < 4; ++fn) {
    const int col = col0 + wn * 64 + fn * 16 + (l & 15);
    const float bb = bias[col];
#pragma unroll
    for (int fm = 0; fm < 4; ++fm) {
#pragma unroll
      for (int q = 0; q < 4; ++q) {
        const int rz = row0 + wm * 64 + fm * 16 + (l >> 4) * 4 + q;
        Cz[(size_t)rz * FDIM + col] = f2bf(fmaxf(acc[fm][fn][q] + bb, 0.f));
      }
    }
  }
}

// ---------------------------------------------------------------------------
// Kernel 2: per-row exact top-64 via threshold candidate pruning on bf16 z.
// Window M=0.025 covers bf16-GEMM noise + bf16-z quantization; f64 boundary
// rescue (coalesced f32 W^T rows) decides exactly at the boundary.
// ---------------------------------------------------------------------------
__global__ __launch_bounds__(256) void topk_kernel(
    const unsigned short* __restrict__ z,  // [Rchunk, FDIM] bf16
    const float* __restrict__ x,           // [Rchunk, DDIM] (chunk-offset)
    const float* __restrict__ wtf,         // [FDIM, DDIM] f32 (W^T)
    const float* __restrict__ benc,        // [FDIM]
    int*   __restrict__ outIdx,            // [Rchunk, TK]
    float* __restrict__ outVal)
{
  const int row = blockIdx.x;
  const int tid = threadIdx.x;
  const unsigned short* zr = z + (size_t)row * FDIM;

  __shared__ int    cIdx[CCAP];
  __shared__ float  cVal[CCAP];
  __shared__ short  sRank[CCAP];
  __shared__ unsigned char selF[CCAP];
  __shared__ int    cnt;
  __shared__ float  sV64;
  __shared__ int    wList[NCAP];
  __shared__ int    nW, winSel;
  __shared__ double dVals[NCAP];
  __shared__ int    keepFlag[NCAP];
  __shared__ double dred[256];

  // ---- candidate scan with bounded threshold retry ----
  float T = 2.25f;
  int nc = 0;
  for (int attempt = 0; attempt < 16; ++attempt) {
    if (tid == 0) cnt = 0;
    __syncthreads();
    for (int i8 = tid; i8 < FDIM / 8; i8 += 256) {
      u16x8 v = ((const u16x8*)zr)[i8];
      const int i0 = i8 * 8;
#pragma unroll
      for (int q = 0; q < 8; ++q) {
        const float f = bf2f(v[q]);
        if (f > T) {
          int p = atomicAdd(&cnt, 1);
          if (p < CCAP) { cIdx[p] = i0 + q; cVal[p] = f; }
        }
      }
    }
    __syncthreads();
    nc = cnt;
    __syncthreads();
    if (nc >= TK && nc <= CCAP) break;
    T += (nc > CCAP) ? 0.25f : -0.5f;
  }
  if (nc > CCAP) nc = CCAP;

  // ---- exact rank among candidates (strict total order) ----
  for (int c = tid; c < nc; c += 256) {
    const float vi = cVal[c];
    const int   ii = cIdx[c];
    int rk = 0;
    for (int j = 0; j < nc; ++j) {
      const float vj = cVal[j];
      rk += (vj > vi) || (vj == vi && cIdx[j] < ii);
    }
    sRank[c] = (short)rk;
    selF[c] = (rk < TK) ? 1 : 0;
    if (rk == TK - 1) sV64 = vi;
  }
  __syncthreads();
  const float v64 = sV64;
  const float M = 0.025f;

  // ---- window collection ----
  if (tid == 0) { nW = 0; winSel = 0; }
  __syncthreads();
  for (int c = tid; c < nc; c += 256) {
    if (fabsf(cVal[c] - v64) <= M) {
      int p = atomicAdd(&nW, 1);
      if (p < NCAP) wList[p] = c;
      if (sRank[c] < TK) atomicAdd(&winSel, 1);
    }
  }
  __syncthreads();
  // guard: if window bottom could fall below scan threshold, rescan row
  if (v64 - M <= T) {
    for (int i8 = tid; i8 < FDIM / 8; i8 += 256) {
      u16x8 v = ((const u16x8*)zr)[i8];
      const int i0 = i8 * 8;
#pragma unroll
      for (int q = 0; q < 8; ++q) {
        const float f = bf2f(v[q]);
        if (f <= T && fabsf(f - v64) <= M) {
          int p = atomicAdd(&cnt, 1);
          if (p < CCAP) {
            cIdx[p] = i0 + q; cVal[p] = f;
            sRank[p] = (short)CCAP; selF[p] = 0;
            int pw = atomicAdd(&nW, 1);
            if (pw < NCAP) wList[pw] = p;
          }
        }
      }
    }
    __syncthreads();
    nc = (cnt < CCAP) ? cnt : CCAP;
  }
  const int nw = (nW < NCAP) ? nW : NCAP;

  // ---- f64 boundary rescue (coalesced f32 W^T rows) ----
  if (nw > winSel) {
    for (int c = 0; c < nw; ++c) {
      const int f = cIdx[wList[c]];
      const float* wr = wtf + (size_t)f * DDIM;
      double part = 0.0;
      for (int k = tid; k < DDIM; k += 256)
        part += (double)x[(size_t)row * DDIM + k] * (double)wr[k];
      dred[tid] = part;
      __syncthreads();
      for (int s = 128; s > 0; s >>= 1) {
        if (tid < s) dred[tid] += dred[tid + s];
        __syncthreads();
      }
      if (tid == 0) dVals[c] = dred[0] + (double)benc[f];
      __syncthreads();
    }
    if (tid == 0) {
      for (int c = 0; c < nw; ++c) keepFlag[c] = 0;
      int take = winSel < nw ? winSel : nw;
      for (int t = 0; t < take; ++t) {
        int best = -1;
        for (int c = 0; c < nw; ++c) {
          if (keepFlag[c]) continue;
          if (best < 0 || dVals[c] > dVals[best] ||
              (dVals[c] == dVals[best] && cIdx[wList[c]] < cIdx[wList[best]]))
            best = c;
        }
        keepFlag[best] = 1;
      }
      for (int c = 0; c < nw; ++c) selF[wList[c]] = (unsigned char)keepFlag[c];
    }
    __syncthreads();
  }

  // ---- emit 64 (idx,val) pairs ordered by feature idx ----
  for (int c = tid; c < nc; c += 256) {
    if (selF[c]) {
      const int myIdx = cIdx[c];
      int pos = 0;
      for (int j = 0; j < nc; ++j)
        pos += (selF[j] && cIdx[j] < myIdx);
      outIdx[(size_t)row * TK + pos] = myIdx;
      outVal[(size_t)row * TK + pos] = cVal[c];
    }
  }
}

// ---------------------------------------------------------------------------
// Kernel 3: decode, output-dim-sliced for L2 locality.
// Grid slice-major: [16 slices][rows]; W_dec slice (16384 x 128 bf16 =
// 4.2 MB) stays L2-hot while all rows' gathers hit it.
// ---------------------------------------------------------------------------
__global__ __launch_bounds__(128) void decode_kernel(
    const int*   __restrict__ idxL,
    const float* __restrict__ valL,
    const unsigned short* __restrict__ Wdb,  // [FDIM][DDIM] bf16
    const float* __restrict__ bd,
    float* __restrict__ out,
    int nrows)
{
  const unsigned bid = blockIdx.x;
  const int slice = bid / (unsigned)nrows;     // slice-major
  const int row   = bid % (unsigned)nrows;
  const int tid = threadIdx.x;
  const int d = slice * 128 + tid;

  __shared__ int   si[TK];
  __shared__ float sv[TK];
  if (tid < TK) {
    si[tid] = idxL[(size_t)row * TK + tid];
    sv[tid] = valL[(size_t)row * TK + tid];
  }
  __syncthreads();

  float a = bd[d];
#pragma unroll 8
  for (int t = 0; t < TK; ++t)
    a = fmaf(sv[t], bf2f(Wdb[(size_t)si[t] * DDIM + d]), a);
  out[(size_t)row * DDIM + d] = a;
}

// ---------------------------------------------------------------------------
extern "C" void kernel_launch(void* const* d_in, const int* in_sizes, int n_in,
                              void* d_out, int out_size, void* d_ws, size_t ws_size,
                              hipStream_t stream) {
  const float* x    = (const float*)d_in[0];
  const float* Wenc = (const float*)d_in[1];
  const float* benc = (const float*)d_in[2];
  const float* Wdec = (const float*)d_in[3];
  const float* bdec = (const float*)d_in[4];
  float* out = (float*)d_out;

  const int D = in_sizes[4];          // 2048
  const int B = in_sizes[0] / D;      // 8192

  // ws layout: idx | val | Wt_f32 | Wt_bf16 | x_h | Wd_b | z bf16 (chunked)
  char* ws = (char*)d_ws;
  size_t off = 0;
  int*   idxL = (int*)ws;            off += (size_t)B * TK * 4;
  float* valL = (float*)(ws + off);  off += (size_t)B * TK * 4;
  off = (off + 255) & ~(size_t)255;
  float*          wtf = (float*)(ws + off);          off += (size_t)FDIM * DDIM * 4;
  unsigned short* wth = (unsigned short*)(ws + off); off += (size_t)FDIM * DDIM * 2;
  unsigned short* xh  = (unsigned short*)(ws + off); off += (size_t)B * DDIM * 2;
  unsigned short* wdb = (unsigned short*)(ws + off); off += (size_t)FDIM * DDIM * 2;
  off = (off + 255) & ~(size_t)255;
  unsigned short* z = (unsigned short*)(ws + off);

  size_t zBytes = (ws_size > off) ? (ws_size - off) : 0;
  long   zRows  = (long)(zBytes / ((size_t)FDIM * 2));
  int R = (int)((zRows / 128) * 128);
  if (R > B) R = B;
  if (R < 128) R = 128;

  conv_x<<<1024, 256, 0, stream>>>(x, xh, B * D / 4);
  conv_w<<<dim3(FDIM / 32, DDIM / 32), 256, 0, stream>>>(Wenc, wtf, wth);
  conv_wd<<<2048, 256, 0, stream>>>(Wdec, wdb, FDIM * DDIM / 4);

  for (int r0 = 0; r0 < B; r0 += R) {
    int rows = (B - r0 < R) ? (B - r0) : R;
    dim3 g(FDIM / 128, rows / 128);
    enc_gemm_bf16<<<g, 256, 0, stream>>>(xh + (size_t)r0 * D, wth, benc, z);
    topk_kernel<<<rows, 256, 0, stream>>>(z, x + (size_t)r0 * D, wtf, benc,
                                          idxL + (size_t)r0 * TK,
                                          valL + (size_t)r0 * TK);
    decode_kernel<<<(DDIM / 128) * rows, 128, 0, stream>>>(
        idxL + (size_t)r0 * TK, valL + (size_t)r0 * TK,
        wdb, bdec, out + (size_t)r0 * D, rows);
  }
}

// Round 9
// 1519.321 us; speedup vs baseline: 2.1478x; 1.0529x over previous
//
#include <hip/hip_runtime.h>
#include <hip/hip_bf16.h>
#include <stdint.h>

#define TK 64
#define FDIM 16384
#define DDIM 2048
#define NCAP 128
#define CCAP 320

typedef __attribute__((ext_vector_type(8))) short bf16x8;
typedef __attribute__((ext_vector_type(8))) unsigned short u16x8;
typedef __attribute__((ext_vector_type(4))) float f32x4;

#define GLL(g, p)                                                        \
  __builtin_amdgcn_global_load_lds(                                      \
      (const __attribute__((address_space(1))) uint32_t*)(g),            \
      (__attribute__((address_space(3))) uint32_t*)(p), 16, 0, 0)

__device__ __forceinline__ unsigned short f2bf(float a) {
  union { float f; uint32_t u; } p; p.f = a;
  uint32_t u = p.u;
  return (unsigned short)((u + 0x7FFFu + ((u >> 16) & 1u)) >> 16);
}
__device__ __forceinline__ float bf2f(unsigned short h) {
  union { uint32_t u; float f; } p; p.u = ((uint32_t)h) << 16; return p.f;
}

// ---------------------------------------------------------------------------
// conv_x: f32 [B][D] -> bf16 [B][D]
// ---------------------------------------------------------------------------
__global__ __launch_bounds__(256) void conv_x(
    const float* __restrict__ x, unsigned short* __restrict__ xh, int n4)
{
  int i = blockIdx.x * 256 + threadIdx.x;
  const int stride = gridDim.x * 256;
  for (; i < n4; i += stride) {
    float4 v = ((const float4*)x)[i];
    ushort4 h;
    h.x = f2bf(v.x); h.y = f2bf(v.y); h.z = f2bf(v.z); h.w = f2bf(v.w);
    ((ushort4*)xh)[i] = h;
  }
}

// ---------------------------------------------------------------------------
// conv_w: W_enc f32 [D][F] -> transposed f32 [F][D] AND bf16 [F][D]
// ---------------------------------------------------------------------------
__global__ __launch_bounds__(256) void conv_w(
    const float* __restrict__ W, float* __restrict__ wtf,
    unsigned short* __restrict__ wh)
{
  __shared__ float t[32][33];
  const int f0 = blockIdx.x * 32, d0 = blockIdx.y * 32;
  const int tr = threadIdx.x >> 3;
  const int tc = (threadIdx.x & 7) * 4;
  float4 v = *(const float4*)(W + (size_t)(d0 + tr) * FDIM + f0 + tc);
  t[tr][tc + 0] = v.x; t[tr][tc + 1] = v.y;
  t[tr][tc + 2] = v.z; t[tr][tc + 3] = v.w;
  __syncthreads();
  float a0 = t[tc + 0][tr], a1 = t[tc + 1][tr];
  float a2 = t[tc + 2][tr], a3 = t[tc + 3][tr];
  *(float4*)(wtf + (size_t)(f0 + tr) * DDIM + d0 + tc) =
      make_float4(a0, a1, a2, a3);
  ushort4 h;
  h.x = f2bf(a0); h.y = f2bf(a1); h.z = f2bf(a2); h.w = f2bf(a3);
  *(ushort4*)(wh + (size_t)(f0 + tr) * DDIM + d0 + tc) = h;
}

// ---------------------------------------------------------------------------
// conv_wd: W_dec f32 [F][D] -> bf16 same layout
// ---------------------------------------------------------------------------
__global__ __launch_bounds__(256) void conv_wd(
    const float* __restrict__ W, unsigned short* __restrict__ Wb, int n4)
{
  int i = blockIdx.x * 256 + threadIdx.x;
  const int stride = gridDim.x * 256;
  for (; i < n4; i += stride) {
    float4 v = ((const float4*)W)[i];
    ushort4 h;
    h.x = f2bf(v.x); h.y = f2bf(v.y); h.z = f2bf(v.z); h.w = f2bf(v.w);
    ((ushort4*)Wb)[i] = h;
  }
}

// ---------------------------------------------------------------------------
// Kernel 1: encode GEMM, single-product bf16 MFMA (m97 structure), bf16 z.
// NEW: panel-major logical block order under the XCD swizzle — each XCD
// works {8 col-blocks x all row-blocks}, keeping its 4MB W^T panel
// L2-resident (FETCH ~1.8GB -> ~0.25GB).
// ---------------------------------------------------------------------------
__global__ __launch_bounds__(256) void enc_gemm_bf16(
    const unsigned short* __restrict__ xh,  // [Rchunk][DDIM] bf16
    const unsigned short* __restrict__ wh,  // [FDIM][DDIM] bf16 (W^T)
    const float* __restrict__ bias,         // [FDIM]
    unsigned short* __restrict__ Cz)        // [Rchunk][FDIM] bf16
{
  __shared__ __align__(16) char smem[16384];
  const int tid = threadIdx.x;
  const int l = tid & 63;
  const int w = tid >> 6;
  const int wm = w >> 1, wn = w & 1;

  // XCD swizzle (contiguous logical range per XCD) + panel-major decode
  const int nbx = gridDim.x;                // 128 col-blocks
  const int nby = gridDim.y;                // row-blocks
  const int lin = blockIdx.y * nbx + blockIdx.x;
  const int nwg = nbx * nby;
  const int cpx = nwg >> 3;                 // nwg % 8 == 0 (nbx=128)
  const int swz = (lin & 7) * cpx + (lin >> 3);
  const int pstripe = 8 * nby;              // blocks per col-panel
  const int p  = swz / pstripe;             // col panel [0,16)
  const int rm = swz % pstripe;
  const int r  = rm >> 3;                   // row-block
  const int ci = rm & 7;                    // col within panel
  const int row0 = r * 128;
  const int col0 = (p * 8 + ci) * 128;

  f32x4 acc[4][4] = {};

  const int sr = tid >> 2;
  const int sg = (tid & 3) ^ ((sr >> 1) & 3);
  const char* gxh = (const char*)xh + (size_t)row0 * 4096 + sg * 16;
  const char* gwh = (const char*)wh + (size_t)col0 * 4096 + sg * 16;

  const int lb = (l & 15) * 64 + (((l >> 4) ^ ((l >> 1) & 3)) << 4);
  const int aoff = wm * 4096 + lb;
  const int boff = 8192 + wn * 4096 + lb;

  for (int k0 = 0; k0 < DDIM; k0 += 32) {
    __syncthreads();
    const size_t kb = (size_t)k0 * 2;
#pragma unroll
    for (int i = 0; i < 2; ++i) {
      const size_t ro = (size_t)(i * 64 + sr) * 4096 + kb;
      char* lp = smem + i * 4096 + w * 1024;
      GLL(gxh + ro, lp);
      GLL(gwh + ro, lp + 8192);
    }
    __syncthreads();

    bf16x8 ah[4], bh[4];
#pragma unroll
    for (int f = 0; f < 4; ++f) {
      ah[f] = *(const bf16x8*)(smem + aoff + f * 1024);
      bh[f] = *(const bf16x8*)(smem + boff + f * 1024);
    }
#pragma unroll
    for (int fm = 0; fm < 4; ++fm)
#pragma unroll
      for (int fn = 0; fn < 4; ++fn)
        acc[fm][fn] = __builtin_amdgcn_mfma_f32_16x16x32_bf16(
            ah[fm], bh[fn], acc[fm][fn], 0, 0, 0);
  }

#pragma unroll
  for (int fn = 0; fn < 4; ++fn) {
    const int col = col0 + wn * 64 + fn * 16 + (l & 15);
    const float bb = bias[col];
#pragma unroll
    for (int fm = 0; fm < 4; ++fm) {
#pragma unroll
      for (int q = 0; q < 4; ++q) {
        const int rz = row0 + wm * 64 + fm * 16 + (l >> 4) * 4 + q;
        Cz[(size_t)rz * FDIM + col] = f2bf(fmaxf(acc[fm][fn][q] + bb, 0.f));
      }
    }
  }
}

// ---------------------------------------------------------------------------
// Kernel 2: per-row exact top-64 via threshold candidate pruning on bf16 z.
// Window M=0.025 covers bf16-GEMM noise + bf16-z quantization; f64 boundary
// rescue (coalesced f32 W^T rows) decides exactly at the boundary.
// ---------------------------------------------------------------------------
__global__ __launch_bounds__(256) void topk_kernel(
    const unsigned short* __restrict__ z,  // [Rchunk, FDIM] bf16
    const float* __restrict__ x,           // [Rchunk, DDIM] (chunk-offset)
    const float* __restrict__ wtf,         // [FDIM, DDIM] f32 (W^T)
    const float* __restrict__ benc,        // [FDIM]
    int*   __restrict__ outIdx,            // [Rchunk, TK]
    float* __restrict__ outVal)
{
  const int row = blockIdx.x;
  const int tid = threadIdx.x;
  const unsigned short* zr = z + (size_t)row * FDIM;

  __shared__ int    cIdx[CCAP];
  __shared__ float  cVal[CCAP];
  __shared__ short  sRank[CCAP];
  __shared__ unsigned char selF[CCAP];
  __shared__ int    cnt;
  __shared__ float  sV64;
  __shared__ int    wList[NCAP];
  __shared__ int    nW, winSel;
  __shared__ double dVals[NCAP];
  __shared__ int    keepFlag[NCAP];
  __shared__ double dred[256];

  // ---- candidate scan with bounded threshold retry ----
  float T = 2.25f;
  int nc = 0;
  for (int attempt = 0; attempt < 16; ++attempt) {
    if (tid == 0) cnt = 0;
    __syncthreads();
    for (int i8 = tid; i8 < FDIM / 8; i8 += 256) {
      u16x8 v = ((const u16x8*)zr)[i8];
      const int i0 = i8 * 8;
#pragma unroll
      for (int q = 0; q < 8; ++q) {
        const float f = bf2f(v[q]);
        if (f > T) {
          int p = atomicAdd(&cnt, 1);
          if (p < CCAP) { cIdx[p] = i0 + q; cVal[p] = f; }
        }
      }
    }
    __syncthreads();
    nc = cnt;
    __syncthreads();
    if (nc >= TK && nc <= CCAP) break;
    T += (nc > CCAP) ? 0.25f : -0.5f;
  }
  if (nc > CCAP) nc = CCAP;

  // ---- exact rank among candidates (strict total order) ----
  for (int c = tid; c < nc; c += 256) {
    const float vi = cVal[c];
    const int   ii = cIdx[c];
    int rk = 0;
    for (int j = 0; j < nc; ++j) {
      const float vj = cVal[j];
      rk += (vj > vi) || (vj == vi && cIdx[j] < ii);
    }
    sRank[c] = (short)rk;
    selF[c] = (rk < TK) ? 1 : 0;
    if (rk == TK - 1) sV64 = vi;
  }
  __syncthreads();
  const float v64 = sV64;
  const float M = 0.025f;

  // ---- window collection ----
  if (tid == 0) { nW = 0; winSel = 0; }
  __syncthreads();
  for (int c = tid; c < nc; c += 256) {
    if (fabsf(cVal[c] - v64) <= M) {
      int p = atomicAdd(&nW, 1);
      if (p < NCAP) wList[p] = c;
      if (sRank[c] < TK) atomicAdd(&winSel, 1);
    }
  }
  __syncthreads();
  // guard: if window bottom could fall below scan threshold, rescan row
  if (v64 - M <= T) {
    for (int i8 = tid; i8 < FDIM / 8; i8 += 256) {
      u16x8 v = ((const u16x8*)zr)[i8];
      const int i0 = i8 * 8;
#pragma unroll
      for (int q = 0; q < 8; ++q) {
        const float f = bf2f(v[q]);
        if (f <= T && fabsf(f - v64) <= M) {
          int p = atomicAdd(&cnt, 1);
          if (p < CCAP) {
            cIdx[p] = i0 + q; cVal[p] = f;
            sRank[p] = (short)CCAP; selF[p] = 0;
            int pw = atomicAdd(&nW, 1);
            if (pw < NCAP) wList[pw] = p;
          }
        }
      }
    }
    __syncthreads();
    nc = (cnt < CCAP) ? cnt : CCAP;
  }
  const int nw = (nW < NCAP) ? nW : NCAP;

  // ---- f64 boundary rescue (coalesced f32 W^T rows) ----
  if (nw > winSel) {
    for (int c = 0; c < nw; ++c) {
      const int f = cIdx[wList[c]];
      const float* wr = wtf + (size_t)f * DDIM;
      double part = 0.0;
      for (int k = tid; k < DDIM; k += 256)
        part += (double)x[(size_t)row * DDIM + k] * (double)wr[k];
      dred[tid] = part;
      __syncthreads();
      for (int s = 128; s > 0; s >>= 1) {
        if (tid < s) dred[tid] += dred[tid + s];
        __syncthreads();
      }
      if (tid == 0) dVals[c] = dred[0] + (double)benc[f];
      __syncthreads();
    }
    if (tid == 0) {
      for (int c = 0; c < nw; ++c) keepFlag[c] = 0;
      int take = winSel < nw ? winSel : nw;
      for (int t = 0; t < take; ++t) {
        int best = -1;
        for (int c = 0; c < nw; ++c) {
          if (keepFlag[c]) continue;
          if (best < 0 || dVals[c] > dVals[best] ||
              (dVals[c] == dVals[best] && cIdx[wList[c]] < cIdx[wList[best]]))
            best = c;
        }
        keepFlag[best] = 1;
      }
      for (int c = 0; c < nw; ++c) selF[wList[c]] = (unsigned char)keepFlag[c];
    }
    __syncthreads();
  }

  // ---- emit 64 (idx,val) pairs ordered by feature idx ----
  for (int c = tid; c < nc; c += 256) {
    if (selF[c]) {
      const int myIdx = cIdx[c];
      int pos = 0;
      for (int j = 0; j < nc; ++j)
        pos += (selF[j] && cIdx[j] < myIdx);
      outIdx[(size_t)row * TK + pos] = myIdx;
      outVal[(size_t)row * TK + pos] = cVal[c];
    }
  }
}

// ---------------------------------------------------------------------------
// Kernel 3: decode, output-dim-sliced for L2 locality (measured-good R8).
// ---------------------------------------------------------------------------
__global__ __launch_bounds__(128) void decode_kernel(
    const int*   __restrict__ idxL,
    const float* __restrict__ valL,
    const unsigned short* __restrict__ Wdb,  // [FDIM][DDIM] bf16
    const float* __restrict__ bd,
    float* __restrict__ out,
    int nrows)
{
  const unsigned bid = blockIdx.x;
  const int slice = bid / (unsigned)nrows;     // slice-major
  const int row   = bid % (unsigned)nrows;
  const int tid = threadIdx.x;
  const int d = slice * 128 + tid;

  __shared__ int   si[TK];
  __shared__ float sv[TK];
  if (tid < TK) {
    si[tid] = idxL[(size_t)row * TK + tid];
    sv[tid] = valL[(size_t)row * TK + tid];
  }
  __syncthreads();

  float a = bd[d];
#pragma unroll 8
  for (int t = 0; t < TK; ++t)
    a = fmaf(sv[t], bf2f(Wdb[(size_t)si[t] * DDIM + d]), a);
  out[(size_t)row * DDIM + d] = a;
}

// ---------------------------------------------------------------------------
extern "C" void kernel_launch(void* const* d_in, const int* in_sizes, int n_in,
                              void* d_out, int out_size, void* d_ws, size_t ws_size,
                              hipStream_t stream) {
  const float* x    = (const float*)d_in[0];
  const float* Wenc = (const float*)d_in[1];
  const float* benc = (const float*)d_in[2];
  const float* Wdec = (const float*)d_in[3];
  const float* bdec = (const float*)d_in[4];
  float* out = (float*)d_out;

  const int D = in_sizes[4];          // 2048
  const int B = in_sizes[0] / D;      // 8192

  // ws layout: idx | val | Wt_f32 | Wt_bf16 | x_h | Wd_b | z bf16 (chunked)
  char* ws = (char*)d_ws;
  size_t off = 0;
  int*   idxL = (int*)ws;            off += (size_t)B * TK * 4;
  float* valL = (float*)(ws + off);  off += (size_t)B * TK * 4;
  off = (off + 255) & ~(size_t)255;
  float*          wtf = (float*)(ws + off);          off += (size_t)FDIM * DDIM * 4;
  unsigned short* wth = (unsigned short*)(ws + off); off += (size_t)FDIM * DDIM * 2;
  unsigned short* xh  = (unsigned short*)(ws + off); off += (size_t)B * DDIM * 2;
  unsigned short* wdb = (unsigned short*)(ws + off); off += (size_t)FDIM * DDIM * 2;
  off = (off + 255) & ~(size_t)255;
  unsigned short* z = (unsigned short*)(ws + off);

  size_t zBytes = (ws_size > off) ? (ws_size - off) : 0;
  long   zRows  = (long)(zBytes / ((size_t)FDIM * 2));
  int R = (int)((zRows / 128) * 128);
  if (R > B) R = B;
  if (R < 128) R = 128;

  conv_x<<<1024, 256, 0, stream>>>(x, xh, B * D / 4);
  conv_w<<<dim3(FDIM / 32, DDIM / 32), 256, 0, stream>>>(Wenc, wtf, wth);
  conv_wd<<<2048, 256, 0, stream>>>(Wdec, wdb, FDIM * DDIM / 4);

  for (int r0 = 0; r0 < B; r0 += R) {
    int rows = (B - r0 < R) ? (B - r0) : R;
    dim3 g(FDIM / 128, rows / 128);
    enc_gemm_bf16<<<g, 256, 0, stream>>>(xh + (size_t)r0 * D, wth, benc, z);
    topk_kernel<<<rows, 256, 0, stream>>>(z, x + (size_t)r0 * D, wtf, benc,
                                          idxL + (size_t)r0 * TK,
                                          valL + (size_t)r0 * TK);
    decode_kernel<<<(DDIM / 128) * rows, 128, 0, stream>>>(
        idxL + (size_t)r0 * TK, valL + (size_t)r0 * TK,
        wdb, bdec, out + (size_t)r0 * D, rows);
  }
}

// Round 10
// 1328.139 us; speedup vs baseline: 2.4570x; 1.1439x over previous
//
#include <hip/hip_runtime.h>
#include <hip/hip_bf16.h>
#include <stdint.h>

#define TK 64
#define FDIM 16384
#define DDIM 2048
#define NCAP 128
#define CCAP 384
#define SLOTS 12
#define TCAND 2.25f

typedef __attribute__((ext_vector_type(8))) short bf16x8;
typedef __attribute__((ext_vector_type(4))) float f32x4;

#define GLL(g, p)                                                        \
  __builtin_amdgcn_global_load_lds(                                      \
      (const __attribute__((address_space(1))) uint32_t*)(g),            \
      (__attribute__((address_space(3))) uint32_t*)(p), 16, 0, 0)

__device__ __forceinline__ unsigned short f2bf(float a) {
  union { float f; uint32_t u; } p; p.f = a;
  uint32_t u = p.u;
  return (unsigned short)((u + 0x7FFFu + ((u >> 16) & 1u)) >> 16);
}
__device__ __forceinline__ float bf2f(unsigned short h) {
  union { uint32_t u; float f; } p; p.u = ((uint32_t)h) << 16; return p.f;
}

// ---------------------------------------------------------------------------
// conv_x: f32 [B][D] -> bf16 [B][D]
// ---------------------------------------------------------------------------
__global__ __launch_bounds__(256) void conv_x(
    const float* __restrict__ x, unsigned short* __restrict__ xh, int n4)
{
  int i = blockIdx.x * 256 + threadIdx.x;
  const int stride = gridDim.x * 256;
  for (; i < n4; i += stride) {
    float4 v = ((const float4*)x)[i];
    ushort4 h;
    h.x = f2bf(v.x); h.y = f2bf(v.y); h.z = f2bf(v.z); h.w = f2bf(v.w);
    ((ushort4*)xh)[i] = h;
  }
}

// ---------------------------------------------------------------------------
// conv_w: W_enc f32 [D][F] -> transposed f32 [F][D] AND bf16 [F][D]
// ---------------------------------------------------------------------------
__global__ __launch_bounds__(256) void conv_w(
    const float* __restrict__ W, float* __restrict__ wtf,
    unsigned short* __restrict__ wh)
{
  __shared__ float t[32][33];
  const int f0 = blockIdx.x * 32, d0 = blockIdx.y * 32;
  const int tr = threadIdx.x >> 3;
  const int tc = (threadIdx.x & 7) * 4;
  float4 v = *(const float4*)(W + (size_t)(d0 + tr) * FDIM + f0 + tc);
  t[tr][tc + 0] = v.x; t[tr][tc + 1] = v.y;
  t[tr][tc + 2] = v.z; t[tr][tc + 3] = v.w;
  __syncthreads();
  float a0 = t[tc + 0][tr], a1 = t[tc + 1][tr];
  float a2 = t[tc + 2][tr], a3 = t[tc + 3][tr];
  *(float4*)(wtf + (size_t)(f0 + tr) * DDIM + d0 + tc) =
      make_float4(a0, a1, a2, a3);
  ushort4 h;
  h.x = f2bf(a0); h.y = f2bf(a1); h.z = f2bf(a2); h.w = f2bf(a3);
  *(ushort4*)(wh + (size_t)(f0 + tr) * DDIM + d0 + tc) = h;
}

// ---------------------------------------------------------------------------
// conv_wd: W_dec f32 [F][D] -> bf16 same layout
// ---------------------------------------------------------------------------
__global__ __launch_bounds__(256) void conv_wd(
    const float* __restrict__ W, unsigned short* __restrict__ Wb, int n4)
{
  int i = blockIdx.x * 256 + threadIdx.x;
  const int stride = gridDim.x * 256;
  for (; i < n4; i += stride) {
    float4 v = ((const float4*)W)[i];
    ushort4 h;
    h.x = f2bf(v.x); h.y = f2bf(v.y); h.z = f2bf(v.z); h.w = f2bf(v.w);
    ((ushort4*)Wb)[i] = h;
  }
}

// ---------------------------------------------------------------------------
// Kernel 1: encode GEMM, single-product bf16 MFMA (m97 structure, panel-major
// XCD order — measured-good R9 core). NO z tensor: epilogue emits candidates
// (z > TCAND, f32 value) into per-(row, col-block) private slots. Counters in
// LDS; global writes are non-atomic & block-private (fixes R5's regression).
// ---------------------------------------------------------------------------
__global__ __launch_bounds__(256) void enc_gemm_bf16(
    const unsigned short* __restrict__ xh,  // [B][DDIM] bf16
    const unsigned short* __restrict__ wh,  // [FDIM][DDIM] bf16 (W^T)
    const float* __restrict__ bias,         // [FDIM]
    unsigned char* __restrict__ counts,     // [128 cb][B]
    uint2* __restrict__ slots,              // [B][128 cb][SLOTS]
    int B)
{
  __shared__ __align__(16) char smem[16384];
  const int tid = threadIdx.x;
  const int l = tid & 63;
  const int w = tid >> 6;
  const int wm = w >> 1, wn = w & 1;

  // XCD swizzle (contiguous logical range per XCD) + panel-major decode
  const int nbx = gridDim.x;                // 128 col-blocks
  const int nby = gridDim.y;                // row-blocks
  const int lin = blockIdx.y * nbx + blockIdx.x;
  const int nwg = nbx * nby;
  const int cpx = nwg >> 3;
  const int swz = (lin & 7) * cpx + (lin >> 3);
  const int pstripe = 8 * nby;
  const int p  = swz / pstripe;
  const int rm = swz % pstripe;
  const int r  = rm >> 3;
  const int ci = rm & 7;
  const int row0 = r * 128;
  const int col0 = (p * 8 + ci) * 128;
  const int cb   = col0 >> 7;

  f32x4 acc[4][4] = {};

  const int sr = tid >> 2;
  const int sg = (tid & 3) ^ ((sr >> 1) & 3);
  const char* gxh = (const char*)xh + (size_t)row0 * 4096 + sg * 16;
  const char* gwh = (const char*)wh + (size_t)col0 * 4096 + sg * 16;

  const int lb = (l & 15) * 64 + (((l >> 4) ^ ((l >> 1) & 3)) << 4);
  const int aoff = wm * 4096 + lb;
  const int boff = 8192 + wn * 4096 + lb;

  for (int k0 = 0; k0 < DDIM; k0 += 32) {
    __syncthreads();
    const size_t kb = (size_t)k0 * 2;
#pragma unroll
    for (int i = 0; i < 2; ++i) {
      const size_t ro = (size_t)(i * 64 + sr) * 4096 + kb;
      char* lp = smem + i * 4096 + w * 1024;
      GLL(gxh + ro, lp);
      GLL(gwh + ro, lp + 8192);
    }
    __syncthreads();

    bf16x8 ah[4], bh[4];
#pragma unroll
    for (int f = 0; f < 4; ++f) {
      ah[f] = *(const bf16x8*)(smem + aoff + f * 1024);
      bh[f] = *(const bf16x8*)(smem + boff + f * 1024);
    }
#pragma unroll
    for (int fm = 0; fm < 4; ++fm)
#pragma unroll
      for (int fn = 0; fn < 4; ++fn)
        acc[fm][fn] = __builtin_amdgcn_mfma_f32_16x16x32_bf16(
            ah[fm], bh[fn], acc[fm][fn], 0, 0, 0);
  }

  // ---- epilogue: bias, threshold-emit into private slots ----
  __syncthreads();                       // all LDS reads done; reuse smem
  uint32_t* rcnt = (uint32_t*)smem;      // 128 per-local-row counters
  if (tid < 128) rcnt[tid] = 0;
  __syncthreads();

#pragma unroll
  for (int fn = 0; fn < 4; ++fn) {
    const int col = col0 + wn * 64 + fn * 16 + (l & 15);
    const float bb = bias[col];
#pragma unroll
    for (int fm = 0; fm < 4; ++fm) {
#pragma unroll
      for (int q = 0; q < 4; ++q) {
        const float zf = acc[fm][fn][q] + bb;   // > TCAND implies > 0 (relu)
        if (zf > TCAND) {
          const int lr = wm * 64 + fm * 16 + (l >> 4) * 4 + q;
          const uint32_t pслot = atomicAdd(&rcnt[lr], 1u);
          if (pслot < SLOTS) {
            const size_t rz = (size_t)(row0 + lr);
            uint2 rec; rec.x = (uint32_t)col; rec.y = __float_as_uint(zf);
            slots[(rz * 128 + cb) * SLOTS + pслot] = rec;
          }
        }
      }
    }
  }
  __syncthreads();
  if (tid < 128) {
    uint32_t c = rcnt[tid];
    counts[(size_t)cb * B + row0 + tid] = (unsigned char)(c > 255u ? 255u : c);
  }
}

// ---------------------------------------------------------------------------
// Kernel 2: per-row exact top-64 from slot lists. Rank by strict
// (val desc, idx asc) = jax tie-break; f64 boundary rescue (verified R2-R9
// semantics). Fallback full f32 recompute from coalesced wtf for the
// ~never-taken guard cases (count<TK, count>CCAP, slot overflow, window
// below TCAND).
// ---------------------------------------------------------------------------
__global__ __launch_bounds__(256) void topk_kernel(
    const unsigned char* __restrict__ countsG,  // [128][B]
    const uint2* __restrict__ slotsG,           // [B][128][SLOTS]
    const float* __restrict__ x,                // [B][DDIM]
    const float* __restrict__ wtf,              // [FDIM][DDIM] f32 (W^T)
    const float* __restrict__ benc,             // [FDIM]
    int*   __restrict__ outIdx,                 // [B][TK]
    float* __restrict__ outVal,
    int B)
{
  const int row = blockIdx.x;
  const int tid = threadIdx.x;
  const float* xr = x + (size_t)row * DDIM;
  const uint2* slotsRow = slotsG + (size_t)row * 128 * SLOTS;

  __shared__ int    cnts[128];
  __shared__ int    sSum, sMax;
  __shared__ int    cIdx[CCAP];
  __shared__ float  cVal[CCAP];
  __shared__ short  sRank[CCAP];
  __shared__ unsigned char selF[CCAP];
  __shared__ int    cnt;
  __shared__ float  sV64;
  __shared__ int    wList[NCAP];
  __shared__ int    nW, winSel;
  __shared__ double dVals[NCAP];
  __shared__ int    keepFlag[NCAP];
  __shared__ double dred[256];

  if (tid == 0) { sSum = 0; sMax = 0; }
  __syncthreads();
  if (tid < 128) {
    int c = countsG[(size_t)tid * B + row];
    cnts[tid] = c;
    atomicAdd(&sSum, c);
    atomicMax(&sMax, c);
  }
  __syncthreads();
  const int total = sSum;
  bool useSlots = (total >= TK) && (total <= CCAP) && (sMax <= SLOTS);
  float Tlow = TCAND;
  int nc = 0;

  for (int pass = 0; pass < 2; ++pass) {
    // ---- build candidate set ----
    if (tid == 0) cnt = 0;
    __syncthreads();
    if (useSlots) {
      for (int s = tid; s < 128 * SLOTS; s += 256) {
        const int cb = s / SLOTS, sl = s - cb * SLOTS;
        if (sl < cnts[cb]) {
          uint2 rec = slotsRow[s];
          int p = atomicAdd(&cnt, 1);
          cIdx[p] = (int)rec.x;
          cVal[p] = __uint_as_float(rec.y);
        }
      }
      __syncthreads();
      nc = cnt;
      __syncthreads();
    } else {
      // fallback: exact f32 recompute of the row's z (coalesced wtf rows)
      float Tloc = Tlow;
      for (int attempt = 0; attempt < 16; ++attempt) {
        if (tid == 0) cnt = 0;
        __syncthreads();
        for (int f = tid; f < FDIM; f += 256) {
          const float* wr = wtf + (size_t)f * DDIM;
          float s = 0.f;
          for (int k = 0; k < DDIM; ++k) s = fmaf(xr[k], wr[k], s);
          const float zv = fmaxf(s + benc[f], 0.f);
          if (zv > Tloc) {
            int p = atomicAdd(&cnt, 1);
            if (p < CCAP) { cIdx[p] = f; cVal[p] = zv; }
          }
        }
        __syncthreads();
        nc = cnt;
        __syncthreads();
        if (nc >= TK && nc <= CCAP) break;
        Tloc += (nc > CCAP) ? 0.2f : -0.2f;
      }
      if (nc > CCAP) nc = CCAP;
    }

    // ---- exact rank among candidates (strict total order) ----
    for (int c = tid; c < nc; c += 256) {
      const float vi = cVal[c];
      const int   ii = cIdx[c];
      int rk = 0;
      for (int j = 0; j < nc; ++j) {
        const float vj = cVal[j];
        rk += (vj > vi) || (vj == vi && cIdx[j] < ii);
      }
      sRank[c] = (short)rk;
      selF[c] = (rk < TK) ? 1 : 0;
      if (rk == TK - 1) sV64 = vi;
    }
    __syncthreads();

    // guard: window may extend below the enc emit threshold -> recompute
    if (useSlots && sV64 - 0.02f <= TCAND) {
      useSlots = false;
      Tlow = sV64 - 0.04f;
      __syncthreads();
      continue;
    }
    break;
  }

  const float v64 = sV64;
  const float M = 0.02f;   // 12 sigma of single-product bf16 z noise

  // ---- window collection ----
  if (tid == 0) { nW = 0; winSel = 0; }
  __syncthreads();
  for (int c = tid; c < nc; c += 256) {
    if (fabsf(cVal[c] - v64) <= M) {
      int p = atomicAdd(&nW, 1);
      if (p < NCAP) wList[p] = c;
      if (sRank[c] < TK) atomicAdd(&winSel, 1);
    }
  }
  __syncthreads();
  const int nw = (nW < NCAP) ? nW : NCAP;

  // ---- f64 boundary rescue (coalesced f32 W^T rows) ----
  if (nw > winSel) {
    for (int c = 0; c < nw; ++c) {
      const int f = cIdx[wList[c]];
      const float* wr = wtf + (size_t)f * DDIM;
      double part = 0.0;
      for (int k = tid; k < DDIM; k += 256)
        part += (double)xr[k] * (double)wr[k];
      dred[tid] = part;
      __syncthreads();
      for (int s = 128; s > 0; s >>= 1) {
        if (tid < s) dred[tid] += dred[tid + s];
        __syncthreads();
      }
      if (tid == 0) dVals[c] = dred[0] + (double)benc[f];
      __syncthreads();
    }
    if (tid == 0) {
      for (int c = 0; c < nw; ++c) keepFlag[c] = 0;
      int take = winSel < nw ? winSel : nw;
      for (int t = 0; t < take; ++t) {
        int best = -1;
        for (int c = 0; c < nw; ++c) {
          if (keepFlag[c]) continue;
          if (best < 0 || dVals[c] > dVals[best] ||
              (dVals[c] == dVals[best] && cIdx[wList[c]] < cIdx[wList[best]]))
            best = c;
        }
        keepFlag[best] = 1;
      }
      for (int c = 0; c < nw; ++c) selF[wList[c]] = (unsigned char)keepFlag[c];
    }
    __syncthreads();
  }

  // ---- emit 64 (idx,val) pairs ordered by feature idx ----
  for (int c = tid; c < nc; c += 256) {
    if (selF[c]) {
      const int myIdx = cIdx[c];
      int pos = 0;
      for (int j = 0; j < nc; ++j)
        pos += (selF[j] && cIdx[j] < myIdx);
      outIdx[(size_t)row * TK + pos] = myIdx;
      outVal[(size_t)row * TK + pos] = cVal[c];
    }
  }
}

// ---------------------------------------------------------------------------
// Kernel 3: decode, output-dim-sliced for L2 locality (measured-good R8/R9).
// ---------------------------------------------------------------------------
__global__ __launch_bounds__(128) void decode_kernel(
    const int*   __restrict__ idxL,
    const float* __restrict__ valL,
    const unsigned short* __restrict__ Wdb,  // [FDIM][DDIM] bf16
    const float* __restrict__ bd,
    float* __restrict__ out,
    int nrows)
{
  const unsigned bid = blockIdx.x;
  const int slice = bid / (unsigned)nrows;     // slice-major
  const int row   = bid % (unsigned)nrows;
  const int tid = threadIdx.x;
  const int d = slice * 128 + tid;

  __shared__ int   si[TK];
  __shared__ float sv[TK];
  if (tid < TK) {
    si[tid] = idxL[(size_t)row * TK + tid];
    sv[tid] = valL[(size_t)row * TK + tid];
  }
  __syncthreads();

  float a = bd[d];
#pragma unroll 8
  for (int t = 0; t < TK; ++t)
    a = fmaf(sv[t], bf2f(Wdb[(size_t)si[t] * DDIM + d]), a);
  out[(size_t)row * DDIM + d] = a;
}

// ---------------------------------------------------------------------------
extern "C" void kernel_launch(void* const* d_in, const int* in_sizes, int n_in,
                              void* d_out, int out_size, void* d_ws, size_t ws_size,
                              hipStream_t stream) {
  const float* x    = (const float*)d_in[0];
  const float* Wenc = (const float*)d_in[1];
  const float* benc = (const float*)d_in[2];
  const float* Wdec = (const float*)d_in[3];
  const float* bdec = (const float*)d_in[4];
  float* out = (float*)d_out;

  const int D = in_sizes[4];          // 2048
  const int B = in_sizes[0] / D;      // 8192

  // ws layout: idx | val | Wt_f32 | Wt_bf16 | x_h | Wd_b | counts | slots
  char* ws = (char*)d_ws;
  size_t off = 0;
  int*   idxL = (int*)ws;            off += (size_t)B * TK * 4;
  float* valL = (float*)(ws + off);  off += (size_t)B * TK * 4;
  off = (off + 255) & ~(size_t)255;
  float*          wtf = (float*)(ws + off);          off += (size_t)FDIM * DDIM * 4;
  unsigned short* wth = (unsigned short*)(ws + off); off += (size_t)FDIM * DDIM * 2;
  unsigned short* xh  = (unsigned short*)(ws + off); off += (size_t)B * DDIM * 2;
  unsigned short* wdb = (unsigned short*)(ws + off); off += (size_t)FDIM * DDIM * 2;
  off = (off + 255) & ~(size_t)255;
  unsigned char*  cntG = (unsigned char*)(ws + off); off += (size_t)128 * B;
  off = (off + 255) & ~(size_t)255;
  uint2*          slots = (uint2*)(ws + off);        off += (size_t)B * 128 * SLOTS * 8;

  conv_x<<<1024, 256, 0, stream>>>(x, xh, B * D / 4);
  conv_w<<<dim3(FDIM / 32, DDIM / 32), 256, 0, stream>>>(Wenc, wtf, wth);
  conv_wd<<<2048, 256, 0, stream>>>(Wdec, wdb, FDIM * DDIM / 4);

  dim3 g(FDIM / 128, B / 128);
  enc_gemm_bf16<<<g, 256, 0, stream>>>(xh, wth, benc, cntG, slots, B);
  topk_kernel<<<B, 256, 0, stream>>>(cntG, slots, x, wtf, benc,
                                     idxL, valL, B);
  decode_kernel<<<(DDIM / 128) * B, 128, 0, stream>>>(
      idxL, valL, wdb, bdec, out, B);
}

// Round 11
// 1216.406 us; speedup vs baseline: 2.6827x; 1.0919x over previous
//
#include <hip/hip_runtime.h>
#include <hip/hip_bf16.h>
#include <stdint.h>

#define TK 64
#define FDIM 16384
#define DDIM 2048
#define NCAP 128
#define CCAP 384
#define SLOTS 12
#define TCAND 2.25f

typedef __attribute__((ext_vector_type(8))) short bf16x8;
typedef __attribute__((ext_vector_type(4))) float f32x4;

#define GLL(g, p)                                                        \
  __builtin_amdgcn_global_load_lds(                                      \
      (const __attribute__((address_space(1))) uint32_t*)(g),            \
      (__attribute__((address_space(3))) uint32_t*)(p), 16, 0, 0)

__device__ __forceinline__ unsigned short f2bf(float a) {
  union { float f; uint32_t u; } p; p.f = a;
  uint32_t u = p.u;
  return (unsigned short)((u + 0x7FFFu + ((u >> 16) & 1u)) >> 16);
}
__device__ __forceinline__ float bf2f(unsigned short h) {
  union { uint32_t u; float f; } p; p.u = ((uint32_t)h) << 16; return p.f;
}

// ---------------------------------------------------------------------------
__global__ __launch_bounds__(256) void conv_x(
    const float* __restrict__ x, unsigned short* __restrict__ xh, int n4)
{
  int i = blockIdx.x * 256 + threadIdx.x;
  const int stride = gridDim.x * 256;
  for (; i < n4; i += stride) {
    float4 v = ((const float4*)x)[i];
    ushort4 h;
    h.x = f2bf(v.x); h.y = f2bf(v.y); h.z = f2bf(v.z); h.w = f2bf(v.w);
    ((ushort4*)xh)[i] = h;
  }
}

// ---------------------------------------------------------------------------
__global__ __launch_bounds__(256) void conv_w(
    const float* __restrict__ W, float* __restrict__ wtf,
    unsigned short* __restrict__ wh)
{
  __shared__ float t[32][33];
  const int f0 = blockIdx.x * 32, d0 = blockIdx.y * 32;
  const int tr = threadIdx.x >> 3;
  const int tc = (threadIdx.x & 7) * 4;
  float4 v = *(const float4*)(W + (size_t)(d0 + tr) * FDIM + f0 + tc);
  t[tr][tc + 0] = v.x; t[tr][tc + 1] = v.y;
  t[tr][tc + 2] = v.z; t[tr][tc + 3] = v.w;
  __syncthreads();
  float a0 = t[tc + 0][tr], a1 = t[tc + 1][tr];
  float a2 = t[tc + 2][tr], a3 = t[tc + 3][tr];
  *(float4*)(wtf + (size_t)(f0 + tr) * DDIM + d0 + tc) =
      make_float4(a0, a1, a2, a3);
  ushort4 h;
  h.x = f2bf(a0); h.y = f2bf(a1); h.z = f2bf(a2); h.w = f2bf(a3);
  *(ushort4*)(wh + (size_t)(f0 + tr) * DDIM + d0 + tc) = h;
}

// ---------------------------------------------------------------------------
__global__ __launch_bounds__(256) void conv_wd(
    const float* __restrict__ W, unsigned short* __restrict__ Wb, int n4)
{
  int i = blockIdx.x * 256 + threadIdx.x;
  const int stride = gridDim.x * 256;
  for (; i < n4; i += stride) {
    float4 v = ((const float4*)W)[i];
    ushort4 h;
    h.x = f2bf(v.x); h.y = f2bf(v.y); h.z = f2bf(v.z); h.w = f2bf(v.w);
    ((ushort4*)Wb)[i] = h;
  }
}

// ---------------------------------------------------------------------------
// Kernel 1: encode GEMM, 256x256 tile, 8 waves (2Mx4N), BK=32 subtile ring
// of 4 LDS buffers, counted vmcnt(8), ONE raw s_barrier per K-step.
// Verified XOR-chunk LDS swizzle (source+read). Slot-emit epilogue (R10).
// ---------------------------------------------------------------------------
#define STAGE(T) do {                                                        \
    const int rb_ = (T) & 3;                                                 \
    const size_t ko_ = (size_t)(T) * 64;                                     \
    const size_t rA0 = (size_t)(row0 + sr4) * 4096 + ko_ + sgo;              \
    GLL(gx + rA0, smem + rb_ * 32768 + wq);                                  \
    const size_t rB0 = (size_t)(col0 + sr4) * 4096 + ko_ + sgo;              \
    GLL(gw + rB0, smem + rb_ * 32768 + 16384 + wq);                          \
    const size_t rA1 = (size_t)(row0 + 128 + sr4) * 4096 + ko_ + sgo;        \
    GLL(gx + rA1, smem + rb_ * 32768 + 8192 + wq);                           \
    const size_t rB1 = (size_t)(col0 + 128 + sr4) * 4096 + ko_ + sgo;        \
    GLL(gw + rB1, smem + rb_ * 32768 + 16384 + 8192 + wq);                   \
  } while (0)

#define KSTEP(S, VMC, DOSTAGE) do {                                          \
    asm volatile("s_waitcnt vmcnt(" #VMC ")" ::: "memory");                  \
    __builtin_amdgcn_s_barrier();                                            \
    const char* tb_ = smem + ((S) & 3) * 32768;                              \
    bf16x8 af[8], bg[4];                                                     \
    _Pragma("unroll") for (int m = 0; m < 8; ++m)                            \
      af[m] = *(const bf16x8*)(tb_ + awm + m * 1024 + lb);                   \
    _Pragma("unroll") for (int n = 0; n < 4; ++n)                            \
      bg[n] = *(const bf16x8*)(tb_ + 16384 + bwn + n * 1024 + lb);           \
    if (DOSTAGE) STAGE((S) + 3);                                             \
    asm volatile("s_waitcnt lgkmcnt(0)" ::: "memory");                       \
    __builtin_amdgcn_sched_barrier(0);                                       \
    __builtin_amdgcn_s_setprio(1);                                           \
    _Pragma("unroll") for (int m = 0; m < 8; ++m)                            \
      _Pragma("unroll") for (int n = 0; n < 4; ++n)                          \
        acc[m][n] = __builtin_amdgcn_mfma_f32_16x16x32_bf16(                 \
            af[m], bg[n], acc[m][n], 0, 0, 0);                               \
    __builtin_amdgcn_s_setprio(0);                                           \
  } while (0)

__global__ __launch_bounds__(512, 2) void enc_gemm_bf16(
    const unsigned short* __restrict__ xh,  // [B][DDIM] bf16
    const unsigned short* __restrict__ wh,  // [FDIM][DDIM] bf16 (W^T)
    const float* __restrict__ bias,         // [FDIM]
    unsigned char* __restrict__ counts,     // [128 cb][B]
    uint2* __restrict__ slots,              // [B][128 cb][SLOTS]
    int B)
{
  __shared__ __align__(16) char smem[131072];  // 4 ring bufs x (A16K + B16K)
  const int tid = threadIdx.x;
  const int l = tid & 63;
  const int w = tid >> 6;                  // 8 waves
  const int wm = w >> 2, wn = w & 3;       // 2 x 4

  // XCD swizzle + panel-major decode (panel = 2 col-tiles = 512 cols = 2MB)
  const int nbx = gridDim.x;               // 64 col-tiles
  const int nby = gridDim.y;               // 32 row-tiles
  const int lin = blockIdx.y * nbx + blockIdx.x;
  const int nwg = nbx * nby;               // 2048, %8 == 0
  const int cpx = nwg >> 3;
  const int swz = (lin & 7) * cpx + (lin >> 3);
  const int pstripe = 2 * nby;
  const int p  = swz / pstripe;
  const int rm = swz % pstripe;
  const int row0 = (rm >> 1) * 256;
  const int col0 = (p * 2 + (rm & 1)) * 256;

  f32x4 acc[8][4] = {};

  // staging constants (verified XOR chunk swizzle, same as R3-R10)
  const int sr4 = tid >> 2;                          // 0..127
  const int sg  = (tid & 3) ^ ((sr4 >> 1) & 3);
  const size_t sgo = (size_t)sg * 16;
  const int wq = w * 1024;                           // wave-uniform LDS base
  const char* gx = (const char*)xh;
  const char* gw = (const char*)wh;

  // read-side lane base (verified): row (l&15), chunk (l>>4)^((l>>1)&3)
  const int lb  = (l & 15) * 64 + (((l >> 4) ^ ((l >> 1) & 3)) << 4);
  const int awm = wm * 8192;
  const int bwn = wn * 4096;

  // prologue: stage subtiles 0,1,2 (12 GLL in flight)
  STAGE(0); STAGE(1); STAGE(2);

  for (int s = 0; s < 61; ++s) KSTEP(s, 8, 1);
  KSTEP(61, 8, 0);
  KSTEP(62, 4, 0);
  KSTEP(63, 0, 0);

  // ---- epilogue: bias + relu + slot emit (256 rows x 2 col-blocks) ----
  __syncthreads();
  uint32_t* rcnt = (uint32_t*)smem;        // 512 counters: [lr][half]
  rcnt[tid] = 0;
  __syncthreads();

#pragma unroll
  for (int n = 0; n < 4; ++n) {
    const int col = col0 + wn * 64 + n * 16 + (l & 15);
    const float bb = bias[col];
    const int half = wn >> 1;
#pragma unroll
    for (int m = 0; m < 8; ++m) {
#pragma unroll
      for (int q = 0; q < 4; ++q) {
        const float zf = acc[m][n][q] + bb;   // > TCAND implies > 0 (relu)
        if (zf > TCAND) {
          const int lr = wm * 128 + m * 16 + (l >> 4) * 4 + q;
          const uint32_t ps = atomicAdd(&rcnt[lr * 2 + half], 1u);
          if (ps < SLOTS) {
            uint2 rec; rec.x = (uint32_t)col; rec.y = __float_as_uint(zf);
            slots[((size_t)(row0 + lr) * 128 + (col0 >> 7) + half) * SLOTS + ps]
                = rec;
          }
        }
      }
    }
  }
  __syncthreads();
  {
    const int lr = tid >> 1, half = tid & 1;
    uint32_t c = rcnt[tid];
    counts[(size_t)((col0 >> 7) + half) * B + row0 + lr] =
        (unsigned char)(c > 255u ? 255u : c);
  }
}

// ---------------------------------------------------------------------------
// Kernel 2: per-row exact top-64 from slot lists (verified R10).
// ---------------------------------------------------------------------------
__global__ __launch_bounds__(256) void topk_kernel(
    const unsigned char* __restrict__ countsG,  // [128][B]
    const uint2* __restrict__ slotsG,           // [B][128][SLOTS]
    const float* __restrict__ x,                // [B][DDIM]
    const float* __restrict__ wtf,              // [FDIM][DDIM] f32 (W^T)
    const float* __restrict__ benc,             // [FDIM]
    int*   __restrict__ outIdx,                 // [B][TK]
    float* __restrict__ outVal,
    int B)
{
  const int row = blockIdx.x;
  const int tid = threadIdx.x;
  const float* xr = x + (size_t)row * DDIM;
  const uint2* slotsRow = slotsG + (size_t)row * 128 * SLOTS;

  __shared__ int    cnts[128];
  __shared__ int    sSum, sMax;
  __shared__ int    cIdx[CCAP];
  __shared__ float  cVal[CCAP];
  __shared__ short  sRank[CCAP];
  __shared__ unsigned char selF[CCAP];
  __shared__ int    cnt;
  __shared__ float  sV64;
  __shared__ int    wList[NCAP];
  __shared__ int    nW, winSel;
  __shared__ double dVals[NCAP];
  __shared__ int    keepFlag[NCAP];
  __shared__ double dred[256];

  if (tid == 0) { sSum = 0; sMax = 0; }
  __syncthreads();
  if (tid < 128) {
    int c = countsG[(size_t)tid * B + row];
    cnts[tid] = c;
    atomicAdd(&sSum, c);
    atomicMax(&sMax, c);
  }
  __syncthreads();
  const int total = sSum;
  bool useSlots = (total >= TK) && (total <= CCAP) && (sMax <= SLOTS);
  float Tlow = TCAND;
  int nc = 0;

  for (int pass = 0; pass < 2; ++pass) {
    if (tid == 0) cnt = 0;
    __syncthreads();
    if (useSlots) {
      for (int s = tid; s < 128 * SLOTS; s += 256) {
        const int cb = s / SLOTS, sl = s - cb * SLOTS;
        if (sl < cnts[cb]) {
          uint2 rec = slotsRow[s];
          int p = atomicAdd(&cnt, 1);
          cIdx[p] = (int)rec.x;
          cVal[p] = __uint_as_float(rec.y);
        }
      }
      __syncthreads();
      nc = cnt;
      __syncthreads();
    } else {
      float Tloc = Tlow;
      for (int attempt = 0; attempt < 16; ++attempt) {
        if (tid == 0) cnt = 0;
        __syncthreads();
        for (int f = tid; f < FDIM; f += 256) {
          const float* wr = wtf + (size_t)f * DDIM;
          float s = 0.f;
          for (int k = 0; k < DDIM; ++k) s = fmaf(xr[k], wr[k], s);
          const float zv = fmaxf(s + benc[f], 0.f);
          if (zv > Tloc) {
            int p = atomicAdd(&cnt, 1);
            if (p < CCAP) { cIdx[p] = f; cVal[p] = zv; }
          }
        }
        __syncthreads();
        nc = cnt;
        __syncthreads();
        if (nc >= TK && nc <= CCAP) break;
        Tloc += (nc > CCAP) ? 0.2f : -0.2f;
      }
      if (nc > CCAP) nc = CCAP;
    }

    for (int c = tid; c < nc; c += 256) {
      const float vi = cVal[c];
      const int   ii = cIdx[c];
      int rk = 0;
      for (int j = 0; j < nc; ++j) {
        const float vj = cVal[j];
        rk += (vj > vi) || (vj == vi && cIdx[j] < ii);
      }
      sRank[c] = (short)rk;
      selF[c] = (rk < TK) ? 1 : 0;
      if (rk == TK - 1) sV64 = vi;
    }
    __syncthreads();

    if (useSlots && sV64 - 0.02f <= TCAND) {
      useSlots = false;
      Tlow = sV64 - 0.04f;
      __syncthreads();
      continue;
    }
    break;
  }

  const float v64 = sV64;
  const float M = 0.02f;

  if (tid == 0) { nW = 0; winSel = 0; }
  __syncthreads();
  for (int c = tid; c < nc; c += 256) {
    if (fabsf(cVal[c] - v64) <= M) {
      int p = atomicAdd(&nW, 1);
      if (p < NCAP) wList[p] = c;
      if (sRank[c] < TK) atomicAdd(&winSel, 1);
    }
  }
  __syncthreads();
  const int nw = (nW < NCAP) ? nW : NCAP;

  if (nw > winSel) {
    for (int c = 0; c < nw; ++c) {
      const int f = cIdx[wList[c]];
      const float* wr = wtf + (size_t)f * DDIM;
      double part = 0.0;
      for (int k = tid; k < DDIM; k += 256)
        part += (double)xr[k] * (double)wr[k];
      dred[tid] = part;
      __syncthreads();
      for (int s = 128; s > 0; s >>= 1) {
        if (tid < s) dred[tid] += dred[tid + s];
        __syncthreads();
      }
      if (tid == 0) dVals[c] = dred[0] + (double)benc[f];
      __syncthreads();
    }
    if (tid == 0) {
      for (int c = 0; c < nw; ++c) keepFlag[c] = 0;
      int take = winSel < nw ? winSel : nw;
      for (int t = 0; t < take; ++t) {
        int best = -1;
        for (int c = 0; c < nw; ++c) {
          if (keepFlag[c]) continue;
          if (best < 0 || dVals[c] > dVals[best] ||
              (dVals[c] == dVals[best] && cIdx[wList[c]] < cIdx[wList[best]]))
            best = c;
        }
        keepFlag[best] = 1;
      }
      for (int c = 0; c < nw; ++c) selF[wList[c]] = (unsigned char)keepFlag[c];
    }
    __syncthreads();
  }

  for (int c = tid; c < nc; c += 256) {
    if (selF[c]) {
      const int myIdx = cIdx[c];
      int pos = 0;
      for (int j = 0; j < nc; ++j)
        pos += (selF[j] && cIdx[j] < myIdx);
      outIdx[(size_t)row * TK + pos] = myIdx;
      outVal[(size_t)row * TK + pos] = cVal[c];
    }
  }
}

// ---------------------------------------------------------------------------
// Kernel 3: decode, output-dim-sliced for L2 locality (verified R8-R10).
// ---------------------------------------------------------------------------
__global__ __launch_bounds__(128) void decode_kernel(
    const int*   __restrict__ idxL,
    const float* __restrict__ valL,
    const unsigned short* __restrict__ Wdb,  // [FDIM][DDIM] bf16
    const float* __restrict__ bd,
    float* __restrict__ out,
    int nrows)
{
  const unsigned bid = blockIdx.x;
  const int slice = bid / (unsigned)nrows;
  const int row   = bid % (unsigned)nrows;
  const int tid = threadIdx.x;
  const int d = slice * 128 + tid;

  __shared__ int   si[TK];
  __shared__ float sv[TK];
  if (tid < TK) {
    si[tid] = idxL[(size_t)row * TK + tid];
    sv[tid] = valL[(size_t)row * TK + tid];
  }
  __syncthreads();

  float a = bd[d];
#pragma unroll 8
  for (int t = 0; t < TK; ++t)
    a = fmaf(sv[t], bf2f(Wdb[(size_t)si[t] * DDIM + d]), a);
  out[(size_t)row * DDIM + d] = a;
}

// ---------------------------------------------------------------------------
extern "C" void kernel_launch(void* const* d_in, const int* in_sizes, int n_in,
                              void* d_out, int out_size, void* d_ws, size_t ws_size,
                              hipStream_t stream) {
  const float* x    = (const float*)d_in[0];
  const float* Wenc = (const float*)d_in[1];
  const float* benc = (const float*)d_in[2];
  const float* Wdec = (const float*)d_in[3];
  const float* bdec = (const float*)d_in[4];
  float* out = (float*)d_out;

  const int D = in_sizes[4];          // 2048
  const int B = in_sizes[0] / D;      // 8192

  // ws layout: idx | val | Wt_f32 | Wt_bf16 | x_h | Wd_b | counts | slots
  char* ws = (char*)d_ws;
  size_t off = 0;
  int*   idxL = (int*)ws;            off += (size_t)B * TK * 4;
  float* valL = (float*)(ws + off);  off += (size_t)B * TK * 4;
  off = (off + 255) & ~(size_t)255;
  float*          wtf = (float*)(ws + off);          off += (size_t)FDIM * DDIM * 4;
  unsigned short* wth = (unsigned short*)(ws + off); off += (size_t)FDIM * DDIM * 2;
  unsigned short* xh  = (unsigned short*)(ws + off); off += (size_t)B * DDIM * 2;
  unsigned short* wdb = (unsigned short*)(ws + off); off += (size_t)FDIM * DDIM * 2;
  off = (off + 255) & ~(size_t)255;
  unsigned char*  cntG = (unsigned char*)(ws + off); off += (size_t)128 * B;
  off = (off + 255) & ~(size_t)255;
  uint2*          slots = (uint2*)(ws + off);        off += (size_t)B * 128 * SLOTS * 8;

  conv_x<<<1024, 256, 0, stream>>>(x, xh, B * D / 4);
  conv_w<<<dim3(FDIM / 32, DDIM / 32), 256, 0, stream>>>(Wenc, wtf, wth);
  conv_wd<<<2048, 256, 0, stream>>>(Wdec, wdb, FDIM * DDIM / 4);

  dim3 g(FDIM / 256, B / 256);
  enc_gemm_bf16<<<g, 512, 0, stream>>>(xh, wth, benc, cntG, slots, B);
  topk_kernel<<<B, 256, 0, stream>>>(cntG, slots, x, wtf, benc,
                                     idxL, valL, B);
  decode_kernel<<<(DDIM / 128) * B, 128, 0, stream>>>(
      idxL, valL, wdb, bdec, out, B);
}

// Round 12
// 1214.331 us; speedup vs baseline: 2.6873x; 1.0017x over previous
//
#include <hip/hip_runtime.h>
#include <hip/hip_bf16.h>
#include <stdint.h>

#define TK 64
#define FDIM 16384
#define DDIM 2048
#define NCAP 128
#define CCAP 384
#define SLOTS 12
#define TCAND 2.25f

typedef __attribute__((ext_vector_type(8))) short bf16x8;
typedef __attribute__((ext_vector_type(4))) float f32x4;

#define GLL(g, p)                                                        \
  __builtin_amdgcn_global_load_lds(                                      \
      (const __attribute__((address_space(1))) uint32_t*)(g),            \
      (__attribute__((address_space(3))) uint32_t*)(p), 16, 0, 0)

__device__ __forceinline__ unsigned short f2bf(float a) {
  union { float f; uint32_t u; } p; p.f = a;
  uint32_t u = p.u;
  return (unsigned short)((u + 0x7FFFu + ((u >> 16) & 1u)) >> 16);
}
__device__ __forceinline__ float bf2f(unsigned short h) {
  union { uint32_t u; float f; } p; p.u = ((uint32_t)h) << 16; return p.f;
}

// ---------------------------------------------------------------------------
__global__ __launch_bounds__(256) void conv_x(
    const float* __restrict__ x, unsigned short* __restrict__ xh, int n4)
{
  int i = blockIdx.x * 256 + threadIdx.x;
  const int stride = gridDim.x * 256;
  for (; i < n4; i += stride) {
    float4 v = ((const float4*)x)[i];
    ushort4 h;
    h.x = f2bf(v.x); h.y = f2bf(v.y); h.z = f2bf(v.z); h.w = f2bf(v.w);
    ((ushort4*)xh)[i] = h;
  }
}

// ---------------------------------------------------------------------------
__global__ __launch_bounds__(256) void conv_w(
    const float* __restrict__ W, float* __restrict__ wtf,
    unsigned short* __restrict__ wh)
{
  __shared__ float t[32][33];
  const int f0 = blockIdx.x * 32, d0 = blockIdx.y * 32;
  const int tr = threadIdx.x >> 3;
  const int tc = (threadIdx.x & 7) * 4;
  float4 v = *(const float4*)(W + (size_t)(d0 + tr) * FDIM + f0 + tc);
  t[tr][tc + 0] = v.x; t[tr][tc + 1] = v.y;
  t[tr][tc + 2] = v.z; t[tr][tc + 3] = v.w;
  __syncthreads();
  float a0 = t[tc + 0][tr], a1 = t[tc + 1][tr];
  float a2 = t[tc + 2][tr], a3 = t[tc + 3][tr];
  *(float4*)(wtf + (size_t)(f0 + tr) * DDIM + d0 + tc) =
      make_float4(a0, a1, a2, a3);
  ushort4 h;
  h.x = f2bf(a0); h.y = f2bf(a1); h.z = f2bf(a2); h.w = f2bf(a3);
  *(ushort4*)(wh + (size_t)(f0 + tr) * DDIM + d0 + tc) = h;
}

// ---------------------------------------------------------------------------
__global__ __launch_bounds__(256) void conv_wd(
    const float* __restrict__ W, unsigned short* __restrict__ Wb, int n4)
{
  int i = blockIdx.x * 256 + threadIdx.x;
  const int stride = gridDim.x * 256;
  for (; i < n4; i += stride) {
    float4 v = ((const float4*)W)[i];
    ushort4 h;
    h.x = f2bf(v.x); h.y = f2bf(v.y); h.z = f2bf(v.z); h.w = f2bf(v.w);
    ((ushort4*)Wb)[i] = h;
  }
}

// ---------------------------------------------------------------------------
// Kernel 1: encode GEMM, 256x256 tile, 8 waves (2Mx4N), BK=32 subtile ring
// of 4 LDS buffers, counted vmcnt(8), ONE raw s_barrier per K-step.
// R12: removed forced lgkmcnt(0)+sched_barrier drain — plain-C++ ds_reads
// let the compiler emit fine-grained lgkmcnt(N) so MFMAs overlap reads.
// Correctness: every read is consumed by an MFMA before the next barrier,
// so the ring-buffer WAR hazard is still barrier-fenced.
// ---------------------------------------------------------------------------
#define STAGE(T) do {                                                        \
    const int rb_ = (T) & 3;                                                 \
    const size_t ko_ = (size_t)(T) * 64;                                     \
    const size_t rA0 = (size_t)(row0 + sr4) * 4096 + ko_ + sgo;              \
    GLL(gx + rA0, smem + rb_ * 32768 + wq);                                  \
    const size_t rB0 = (size_t)(col0 + sr4) * 4096 + ko_ + sgo;              \
    GLL(gw + rB0, smem + rb_ * 32768 + 16384 + wq);                          \
    const size_t rA1 = (size_t)(row0 + 128 + sr4) * 4096 + ko_ + sgo;        \
    GLL(gx + rA1, smem + rb_ * 32768 + 8192 + wq);                           \
    const size_t rB1 = (size_t)(col0 + 128 + sr4) * 4096 + ko_ + sgo;        \
    GLL(gw + rB1, smem + rb_ * 32768 + 16384 + 8192 + wq);                   \
  } while (0)

#define KSTEP(S, VMC, DOSTAGE) do {                                          \
    asm volatile("s_waitcnt vmcnt(" #VMC ")" ::: "memory");                  \
    __builtin_amdgcn_s_barrier();                                            \
    const char* tb_ = smem + ((S) & 3) * 32768;                              \
    bf16x8 af[8], bg[4];                                                     \
    _Pragma("unroll") for (int m = 0; m < 8; ++m)                            \
      af[m] = *(const bf16x8*)(tb_ + awm + m * 1024 + lb);                   \
    _Pragma("unroll") for (int n = 0; n < 4; ++n)                            \
      bg[n] = *(const bf16x8*)(tb_ + 16384 + bwn + n * 1024 + lb);           \
    if (DOSTAGE) STAGE((S) + 3);                                             \
    __builtin_amdgcn_s_setprio(1);                                           \
    _Pragma("unroll") for (int m = 0; m < 8; ++m)                            \
      _Pragma("unroll") for (int n = 0; n < 4; ++n)                          \
        acc[m][n] = __builtin_amdgcn_mfma_f32_16x16x32_bf16(                 \
            af[m], bg[n], acc[m][n], 0, 0, 0);                               \
    __builtin_amdgcn_s_setprio(0);                                           \
  } while (0)

__global__ __launch_bounds__(512, 2) void enc_gemm_bf16(
    const unsigned short* __restrict__ xh,  // [B][DDIM] bf16
    const unsigned short* __restrict__ wh,  // [FDIM][DDIM] bf16 (W^T)
    const float* __restrict__ bias,         // [FDIM]
    unsigned char* __restrict__ counts,     // [128 cb][B]
    uint2* __restrict__ slots,              // [B][128 cb][SLOTS]
    int B)
{
  __shared__ __align__(16) char smem[131072];  // 4 ring bufs x (A16K + B16K)
  const int tid = threadIdx.x;
  const int l = tid & 63;
  const int w = tid >> 6;                  // 8 waves
  const int wm = w >> 2, wn = w & 3;       // 2 x 4

  // XCD swizzle + panel-major decode (panel = 2 col-tiles = 512 cols = 2MB)
  const int nbx = gridDim.x;               // 64 col-tiles
  const int nby = gridDim.y;               // 32 row-tiles
  const int lin = blockIdx.y * nbx + blockIdx.x;
  const int nwg = nbx * nby;               // 2048, %8 == 0
  const int cpx = nwg >> 3;
  const int swz = (lin & 7) * cpx + (lin >> 3);
  const int pstripe = 2 * nby;
  const int p  = swz / pstripe;
  const int rm = swz % pstripe;
  const int row0 = (rm >> 1) * 256;
  const int col0 = (p * 2 + (rm & 1)) * 256;

  f32x4 acc[8][4] = {};

  // staging constants (verified XOR chunk swizzle, same as R3-R11)
  const int sr4 = tid >> 2;                          // 0..127
  const int sg  = (tid & 3) ^ ((sr4 >> 1) & 3);
  const size_t sgo = (size_t)sg * 16;
  const int wq = w * 1024;                           // wave-uniform LDS base
  const char* gx = (const char*)xh;
  const char* gw = (const char*)wh;

  // read-side lane base (verified): row (l&15), chunk (l>>4)^((l>>1)&3)
  const int lb  = (l & 15) * 64 + (((l >> 4) ^ ((l >> 1) & 3)) << 4);
  const int awm = wm * 8192;
  const int bwn = wn * 4096;

  // prologue: stage subtiles 0,1,2 (12 GLL in flight)
  STAGE(0); STAGE(1); STAGE(2);

  for (int s = 0; s < 61; ++s) KSTEP(s, 8, 1);
  KSTEP(61, 8, 0);
  KSTEP(62, 4, 0);
  KSTEP(63, 0, 0);

  // ---- epilogue: bias + relu + slot emit (256 rows x 2 col-blocks) ----
  __syncthreads();
  uint32_t* rcnt = (uint32_t*)smem;        // 512 counters: [lr][half]
  rcnt[tid] = 0;
  __syncthreads();

#pragma unroll
  for (int n = 0; n < 4; ++n) {
    const int col = col0 + wn * 64 + n * 16 + (l & 15);
    const float bb = bias[col];
    const int half = wn >> 1;
#pragma unroll
    for (int m = 0; m < 8; ++m) {
#pragma unroll
      for (int q = 0; q < 4; ++q) {
        const float zf = acc[m][n][q] + bb;   // > TCAND implies > 0 (relu)
        if (zf > TCAND) {
          const int lr = wm * 128 + m * 16 + (l >> 4) * 4 + q;
          const uint32_t ps = atomicAdd(&rcnt[lr * 2 + half], 1u);
          if (ps < SLOTS) {
            uint2 rec; rec.x = (uint32_t)col; rec.y = __float_as_uint(zf);
            slots[((size_t)(row0 + lr) * 128 + (col0 >> 7) + half) * SLOTS + ps]
                = rec;
          }
        }
      }
    }
  }
  __syncthreads();
  {
    const int lr = tid >> 1, half = tid & 1;
    uint32_t c = rcnt[tid];
    counts[(size_t)((col0 >> 7) + half) * B + row0 + lr] =
        (unsigned char)(c > 255u ? 255u : c);
  }
}

// ---------------------------------------------------------------------------
// Kernel 2: per-row exact top-64 from slot lists (verified R10/R11).
// ---------------------------------------------------------------------------
__global__ __launch_bounds__(256) void topk_kernel(
    const unsigned char* __restrict__ countsG,  // [128][B]
    const uint2* __restrict__ slotsG,           // [B][128][SLOTS]
    const float* __restrict__ x,                // [B][DDIM]
    const float* __restrict__ wtf,              // [FDIM][DDIM] f32 (W^T)
    const float* __restrict__ benc,             // [FDIM]
    int*   __restrict__ outIdx,                 // [B][TK]
    float* __restrict__ outVal,
    int B)
{
  const int row = blockIdx.x;
  const int tid = threadIdx.x;
  const float* xr = x + (size_t)row * DDIM;
  const uint2* slotsRow = slotsG + (size_t)row * 128 * SLOTS;

  __shared__ int    cnts[128];
  __shared__ int    sSum, sMax;
  __shared__ int    cIdx[CCAP];
  __shared__ float  cVal[CCAP];
  __shared__ short  sRank[CCAP];
  __shared__ unsigned char selF[CCAP];
  __shared__ int    cnt;
  __shared__ float  sV64;
  __shared__ int    wList[NCAP];
  __shared__ int    nW, winSel;
  __shared__ double dVals[NCAP];
  __shared__ int    keepFlag[NCAP];
  __shared__ double dred[256];

  if (tid == 0) { sSum = 0; sMax = 0; }
  __syncthreads();
  if (tid < 128) {
    int c = countsG[(size_t)tid * B + row];
    cnts[tid] = c;
    atomicAdd(&sSum, c);
    atomicMax(&sMax, c);
  }
  __syncthreads();
  const int total = sSum;
  bool useSlots = (total >= TK) && (total <= CCAP) && (sMax <= SLOTS);
  float Tlow = TCAND;
  int nc = 0;

  for (int pass = 0; pass < 2; ++pass) {
    if (tid == 0) cnt = 0;
    __syncthreads();
    if (useSlots) {
      for (int s = tid; s < 128 * SLOTS; s += 256) {
        const int cb = s / SLOTS, sl = s - cb * SLOTS;
        if (sl < cnts[cb]) {
          uint2 rec = slotsRow[s];
          int p = atomicAdd(&cnt, 1);
          cIdx[p] = (int)rec.x;
          cVal[p] = __uint_as_float(rec.y);
        }
      }
      __syncthreads();
      nc = cnt;
      __syncthreads();
    } else {
      float Tloc = Tlow;
      for (int attempt = 0; attempt < 16; ++attempt) {
        if (tid == 0) cnt = 0;
        __syncthreads();
        for (int f = tid; f < FDIM; f += 256) {
          const float* wr = wtf + (size_t)f * DDIM;
          float s = 0.f;
          for (int k = 0; k < DDIM; ++k) s = fmaf(xr[k], wr[k], s);
          const float zv = fmaxf(s + benc[f], 0.f);
          if (zv > Tloc) {
            int p = atomicAdd(&cnt, 1);
            if (p < CCAP) { cIdx[p] = f; cVal[p] = zv; }
          }
        }
        __syncthreads();
        nc = cnt;
        __syncthreads();
        if (nc >= TK && nc <= CCAP) break;
        Tloc += (nc > CCAP) ? 0.2f : -0.2f;
      }
      if (nc > CCAP) nc = CCAP;
    }

    for (int c = tid; c < nc; c += 256) {
      const float vi = cVal[c];
      const int   ii = cIdx[c];
      int rk = 0;
      for (int j = 0; j < nc; ++j) {
        const float vj = cVal[j];
        rk += (vj > vi) || (vj == vi && cIdx[j] < ii);
      }
      sRank[c] = (short)rk;
      selF[c] = (rk < TK) ? 1 : 0;
      if (rk == TK - 1) sV64 = vi;
    }
    __syncthreads();

    if (useSlots && sV64 - 0.02f <= TCAND) {
      useSlots = false;
      Tlow = sV64 - 0.04f;
      __syncthreads();
      continue;
    }
    break;
  }

  const float v64 = sV64;
  const float M = 0.02f;

  if (tid == 0) { nW = 0; winSel = 0; }
  __syncthreads();
  for (int c = tid; c < nc; c += 256) {
    if (fabsf(cVal[c] - v64) <= M) {
      int p = atomicAdd(&nW, 1);
      if (p < NCAP) wList[p] = c;
      if (sRank[c] < TK) atomicAdd(&winSel, 1);
    }
  }
  __syncthreads();
  const int nw = (nW < NCAP) ? nW : NCAP;

  if (nw > winSel) {
    for (int c = 0; c < nw; ++c) {
      const int f = cIdx[wList[c]];
      const float* wr = wtf + (size_t)f * DDIM;
      double part = 0.0;
      for (int k = tid; k < DDIM; k += 256)
        part += (double)xr[k] * (double)wr[k];
      dred[tid] = part;
      __syncthreads();
      for (int s = 128; s > 0; s >>= 1) {
        if (tid < s) dred[tid] += dred[tid + s];
        __syncthreads();
      }
      if (tid == 0) dVals[c] = dred[0] + (double)benc[f];
      __syncthreads();
    }
    if (tid == 0) {
      for (int c = 0; c < nw; ++c) keepFlag[c] = 0;
      int take = winSel < nw ? winSel : nw;
      for (int t = 0; t < take; ++t) {
        int best = -1;
        for (int c = 0; c < nw; ++c) {
          if (keepFlag[c]) continue;
          if (best < 0 || dVals[c] > dVals[best] ||
              (dVals[c] == dVals[best] && cIdx[wList[c]] < cIdx[wList[best]]))
            best = c;
        }
        keepFlag[best] = 1;
      }
      for (int c = 0; c < nw; ++c) selF[wList[c]] = (unsigned char)keepFlag[c];
    }
    __syncthreads();
  }

  for (int c = tid; c < nc; c += 256) {
    if (selF[c]) {
      const int myIdx = cIdx[c];
      int pos = 0;
      for (int j = 0; j < nc; ++j)
        pos += (selF[j] && cIdx[j] < myIdx);
      outIdx[(size_t)row * TK + pos] = myIdx;
      outVal[(size_t)row * TK + pos] = cVal[c];
    }
  }
}

// ---------------------------------------------------------------------------
// Kernel 3: decode, output-dim-sliced for L2 locality (verified R8-R11).
// ---------------------------------------------------------------------------
__global__ __launch_bounds__(128) void decode_kernel(
    const int*   __restrict__ idxL,
    const float* __restrict__ valL,
    const unsigned short* __restrict__ Wdb,  // [FDIM][DDIM] bf16
    const float* __restrict__ bd,
    float* __restrict__ out,
    int nrows)
{
  const unsigned bid = blockIdx.x;
  const int slice = bid / (unsigned)nrows;
  const int row   = bid % (unsigned)nrows;
  const int tid = threadIdx.x;
  const int d = slice * 128 + tid;

  __shared__ int   si[TK];
  __shared__ float sv[TK];
  if (tid < TK) {
    si[tid] = idxL[(size_t)row * TK + tid];
    sv[tid] = valL[(size_t)row * TK + tid];
  }
  __syncthreads();

  float a = bd[d];
#pragma unroll 8
  for (int t = 0; t < TK; ++t)
    a = fmaf(sv[t], bf2f(Wdb[(size_t)si[t] * DDIM + d]), a);
  out[(size_t)row * DDIM + d] = a;
}

// ---------------------------------------------------------------------------
extern "C" void kernel_launch(void* const* d_in, const int* in_sizes, int n_in,
                              void* d_out, int out_size, void* d_ws, size_t ws_size,
                              hipStream_t stream) {
  const float* x    = (const float*)d_in[0];
  const float* Wenc = (const float*)d_in[1];
  const float* benc = (const float*)d_in[2];
  const float* Wdec = (const float*)d_in[3];
  const float* bdec = (const float*)d_in[4];
  float* out = (float*)d_out;

  const int D = in_sizes[4];          // 2048
  const int B = in_sizes[0] / D;      // 8192

  // ws layout: idx | val | Wt_f32 | Wt_bf16 | x_h | Wd_b | counts | slots
  char* ws = (char*)d_ws;
  size_t off = 0;
  int*   idxL = (int*)ws;            off += (size_t)B * TK * 4;
  float* valL = (float*)(ws + off);  off += (size_t)B * TK * 4;
  off = (off + 255) & ~(size_t)255;
  float*          wtf = (float*)(ws + off);          off += (size_t)FDIM * DDIM * 4;
  unsigned short* wth = (unsigned short*)(ws + off); off += (size_t)FDIM * DDIM * 2;
  unsigned short* xh  = (unsigned short*)(ws + off); off += (size_t)B * DDIM * 2;
  unsigned short* wdb = (unsigned short*)(ws + off); off += (size_t)FDIM * DDIM * 2;
  off = (off + 255) & ~(size_t)255;
  unsigned char*  cntG = (unsigned char*)(ws + off); off += (size_t)128 * B;
  off = (off + 255) & ~(size_t)255;
  uint2*          slots = (uint2*)(ws + off);        off += (size_t)B * 128 * SLOTS * 8;

  conv_x<<<1024, 256, 0, stream>>>(x, xh, B * D / 4);
  conv_w<<<dim3(FDIM / 32, DDIM / 32), 256, 0, stream>>>(Wenc, wtf, wth);
  conv_wd<<<2048, 256, 0, stream>>>(Wdec, wdb, FDIM * DDIM / 4);

  dim3 g(FDIM / 256, B / 256);
  enc_gemm_bf16<<<g, 512, 0, stream>>>(xh, wth, benc, cntG, slots, B);
  topk_kernel<<<B, 256, 0, stream>>>(cntG, slots, x, wtf, benc,
                                     idxL, valL, B);
  decode_kernel<<<(DDIM / 128) * B, 128, 0, stream>>>(
      idxL, valL, wdb, bdec, out, B);
}